// Round 15
// baseline (683.781 us; speedup 1.0000x reference)
//
#include <hip/hip_runtime.h>

typedef unsigned short u16;
typedef unsigned int u32;
typedef short bf16x8 __attribute__((ext_vector_type(8)));
typedef float f32x4 __attribute__((ext_vector_type(4)));
typedef unsigned short u16x8 __attribute__((ext_vector_type(8)));
typedef unsigned short u16x4 __attribute__((ext_vector_type(4)));

#define DEVFN static __device__ __forceinline__

DEVFN u16 f2b(float f) {
    u32 u = __builtin_bit_cast(u32, f);
    u += 0x7FFFu + ((u >> 16) & 1u);
    return (u16)(u >> 16);
}
DEVFN float b2f(u16 h) {
    u32 u = ((u32)h) << 16;
    return __builtin_bit_cast(float, u);
}

typedef const __attribute__((address_space(1))) unsigned int glb_u32;
typedef __attribute__((address_space(3))) unsigned int lds_u32;
DEVFN void gload_lds16(const u16* g, u16* l) {
    __builtin_amdgcn_global_load_lds((glb_u32*)g, (lds_u32*)l, 16, 0, 0);
}

// ---------------------------------------------------------------- prep ----
__global__ void k_prep(const float* __restrict__ qkvw, const float* __restrict__ pjw,
                       u16* __restrict__ qkvwb, u16* __restrict__ pjwb) {
    int id = blockIdx.x * 256 + threadIdx.x;
    if (id < 196608) qkvwb[id] = f2b(qkvw[id]);
    if (id < 65536)  pjwb[id]  = f2b(pjw[id]);
}

__global__ void k_cpb(const float* __restrict__ w1, const float* __restrict__ b1,
                      const float* __restrict__ w2, float* __restrict__ bt) {
    int p = threadIdx.x;
    if (p >= 225) return;
    int d0 = p / 15, d1 = p % 15;
    float v0 = (float)(d0 - 7) * (8.0f / 7.0f);
    float v1 = (float)(d1 - 7) * (8.0f / 7.0f);
    float t0 = copysignf(log2f(fabsf(v0) + 1.0f) * (1.0f / 3.0f), v0);
    float t1 = copysignf(log2f(fabsf(v1) + 1.0f) * (1.0f / 3.0f), v1);
    float s[8] = {0.f, 0.f, 0.f, 0.f, 0.f, 0.f, 0.f, 0.f};
    for (int d = 0; d < 256; ++d) {
        float h = t0 * w1[2 * d] + t1 * w1[2 * d + 1] + b1[d];
        h = fmaxf(h, 0.0f);
        #pragma unroll
        for (int hh = 0; hh < 8; ++hh) s[hh] += h * w2[hh * 256 + d];
    }
    #pragma unroll
    for (int hh = 0; hh < 8; ++hh) bt[p * 8 + hh] = s[hh];
}

// TRANSPOSED bias table: biasT[h][k][q]
__global__ void k_bias(const float* __restrict__ bt, float* __restrict__ biasT) {
    int id = blockIdx.x * 256 + threadIdx.x;  // id = k*64 + q
    int kq = id >> 6, q = id & 63;
    int d0 = (q >> 3) - (kq >> 3) + 7;
    int d1 = (q & 7) - (kq & 7) + 7;
    int p = d0 * 15 + d1;
    #pragma unroll
    for (int h = 0; h < 8; ++h)
        biasT[h * 4096 + id] = 16.0f / (1.0f + expf(-bt[p * 8 + h]));
}

// ---------------------------------------------------------------- xcvt ----
// R13 verbatim: x fp32 NCHW -> bf16 in swizzled tile order, XCD-aligned.
__global__ __launch_bounds__(256) void k_xcvt(const float* __restrict__ x,
                                              u16* __restrict__ xt) {
    const int bid = blockIdx.x;              // 4096 = 8 xcd * 128 rowblk * 4 chunk
    const int xcd = bid & 7;
    const int i = bid >> 3;                  // 0..511
    const int rowblk = xcd * 128 + (i >> 2);
    const int c = i & 3;
    const int tid = threadIdx.x;
    const int g = tid & 7;                   // 8-ch group 0..7
    const int tseg = tid >> 3;               // 0..31
    const int tok0 = tseg * 4;
    const float* src = x + ((size_t)(rowblk >> 7) * 256 + c * 64 + g * 8) * 16384
                         + (rowblk & 127) * 128 + tok0;
    float4 v[8];
    #pragma unroll
    for (int j = 0; j < 8; ++j)
        v[j] = *(const float4*)(src + (size_t)j * 16384);
    u16x8 o0, o1, o2, o3;
    #pragma unroll
    for (int j = 0; j < 8; ++j) {
        o0[j] = f2b(v[j].x);
        o1[j] = f2b(v[j].y);
        o2[j] = f2b(v[j].z);
        o3[j] = f2b(v[j].w);
    }
    const int s0 = g ^ ((tseg ^ (tok0 + 0)) & 7);
    const int s1 = g ^ ((tseg ^ (tok0 + 1)) & 7);
    const int s2 = g ^ ((tseg ^ (tok0 + 2)) & 7);
    const int s3 = g ^ ((tseg ^ (tok0 + 3)) & 7);
    u16* dst = xt + ((size_t)rowblk * 4 + c) * 8192;
    *(u16x8*)&dst[(tok0 + 0) * 64 + (s0 << 3)] = o0;
    *(u16x8*)&dst[(tok0 + 1) * 64 + (s1 << 3)] = o1;
    *(u16x8*)&dst[(tok0 + 2) * 64 + (s2 << 3)] = o2;
    *(u16x8*)&dst[(tok0 + 3) * 64 + (s3 << 3)] = o3;
}

// ---------------------------------------------------------------- qkv -----
// R13 verbatim (proven 145us): gload_lds staging + weight-register dbuf.
// __launch_bounds__(256,3): (256,4)'s 128-VGPR cap spills (R4/R6/R9/R12).
__global__ __launch_bounds__(256, 3) void k_qkv(
    const u16* __restrict__ xt, const u16* __restrict__ qkvw,
    const float* __restrict__ qkvb,
    u16* __restrict__ gq, u16* __restrict__ gk, u16* __restrict__ wv_g) {
    __shared__ __align__(16) u16 Xs[2][8192];  // [128 tok][64 ch] swizzled

    const int bid = blockIdx.x;                 // 6144 = 8 xcd * 128 rowblk * 6 ny
    const int xcd = bid & 7;
    const int idx = bid >> 3;
    const int ny = idx % 6;
    const int rowblk = xcd * 128 + idx / 6;
    const int b = rowblk >> 7, row = rowblk & 127;
    const int which = ny >> 1, half = ny & 1;

    const int tid = threadIdx.x;
    const int wave = tid >> 6, l = tid & 63, col = l & 15, quad = l >> 4;
    const int th = wave >> 1;
    const int oq = wave & 1;
    const int obase = half * 128 + oq * 64;

    int orow[4];
    #pragma unroll
    for (int nt = 0; nt < 4; ++nt) {
        const int oo = obase + nt * 16 + col;
        orow[nt] = (oo >> 5) * 96 + which * 32 + (oo & 31);
    }

    f32x4 acc[4][4];                            // [nt(och)][mt(tok)]
    #pragma unroll
    for (int i = 0; i < 4; ++i)
        #pragma unroll
        for (int j = 0; j < 4; ++j) acc[i][j] = f32x4{0.f, 0.f, 0.f, 0.f};

    const u16* xtb = xt + (size_t)rowblk * 32768;

    auto stage = [&](int c, int buf) {
        const u16* src = xtb + c * 8192 + wave * 2048 + l * 8;
        u16* dst = &Xs[buf][wave * 2048];
        #pragma unroll
        for (int i = 0; i < 4; ++i)
            gload_lds16(src + i * 512, dst + i * 512);
    };
    auto loadW = [&](int c, bf16x8* bw) {
        #pragma unroll
        for (int kk = 0; kk < 2; ++kk)
            #pragma unroll
            for (int nt = 0; nt < 4; ++nt)
                bw[kk * 4 + nt] = *(const bf16x8*)&qkvw[(size_t)orow[nt] * 256 +
                                                        c * 64 + kk * 32 + quad * 8];
    };
    auto gemm = [&](int buf, const bf16x8* bw) {
        #pragma unroll
        for (int kk = 0; kk < 2; ++kk) {
            const int lchunk = kk * 4 + quad;
            bf16x8 af[4];
            #pragma unroll
            for (int mt = 0; mt < 4; ++mt) {
                const int tok = th * 64 + mt * 16 + col;
                const int slot = lchunk ^ (((tok >> 2) ^ tok) & 7);
                af[mt] = *(const bf16x8*)&Xs[buf][tok * 64 + (slot << 3)];
            }
            #pragma unroll
            for (int nt = 0; nt < 4; ++nt)
                #pragma unroll
                for (int mt = 0; mt < 4; ++mt)
                    acc[nt][mt] = __builtin_amdgcn_mfma_f32_16x16x32_bf16(
                        bw[kk * 4 + nt], af[mt], acc[nt][mt], 0, 0, 0);
        }
    };

    bf16x8 bwA[8], bwB[8];
    stage(0, 0);
    loadW(0, bwA);
    __syncthreads();
    #pragma unroll
    for (int c = 0; c < 4; ++c) {
        if (c < 3) {
            stage(c + 1, (c + 1) & 1);          // async prefetch (T14)
            loadW(c + 1, (c & 1) ? bwA : bwB);  // weight prefetch
        }
        gemm(c & 1, (c & 1) ? bwB : bwA);
        __syncthreads();
    }

    // epilogue: D[och][tok]
    const int hA = obase >> 5;
    f32x4 bqv[4];
    #pragma unroll
    for (int nt = 0; nt < 4; ++nt) {
        const int oo = obase + nt * 16 + quad * 4;
        bqv[nt] = *(const f32x4*)&qkvb[(oo >> 5) * 96 + which * 32 + (oo & 31)];
    }
    #pragma unroll
    for (int mt = 0; mt < 4; ++mt) {
        const int tok = th * 64 + mt * 16 + col;
        const int win = b * 256 + (row >> 3) * 16 + (tok >> 3);
        const int tk = (row & 7) * 8 + (tok & 7);
        float v[4][4];
        #pragma unroll
        for (int nt = 0; nt < 4; ++nt)
            #pragma unroll
            for (int r = 0; r < 4; ++r)
                v[nt][r] = acc[nt][mt][r] + bqv[nt][r];
        if (which < 2) {
            float sA = 0.f, sB = 0.f;
            #pragma unroll
            for (int r = 0; r < 4; ++r) {
                sA += v[0][r] * v[0][r] + v[1][r] * v[1][r];
                sB += v[2][r] * v[2][r] + v[3][r] * v[3][r];
            }
            sA += __shfl_xor(sA, 16, 64);
            sA += __shfl_xor(sA, 32, 64);
            sB += __shfl_xor(sB, 16, 64);
            sB += __shfl_xor(sB, 32, 64);
            const float iA = 1.0f / fmaxf(sqrtf(sA), 1e-12f);
            const float iB = 1.0f / fmaxf(sqrtf(sB), 1e-12f);
            #pragma unroll
            for (int r = 0; r < 4; ++r) {
                v[0][r] *= iA; v[1][r] *= iA;
                v[2][r] *= iB; v[3][r] *= iB;
            }
        }
        #pragma unroll
        for (int nt = 0; nt < 4; ++nt) {
            u16x4 ov;
            #pragma unroll
            for (int r = 0; r < 4; ++r) ov[r] = f2b(v[nt][r]);
            if (which == 2) {
                *(u16x4*)&wv_g[((size_t)win * 64 + tk) * 256 + obase + nt * 16 + quad * 4] = ov;
            } else {
                u16* G = (which == 0) ? gq : gk;
                const int h = hA + (nt >> 1);
                const int d = (nt & 1) * 16 + quad * 4;
                *(u16x4*)&G[((size_t)(win * 8 + h) * 64 + tk) * 32 + d] = ov;
            }
        }
    }
}

// ---------------------------------------------------------------- attn ----
// R13 verbatim: S^T layout, in-register softmax, P^T from regs, XCD-aligned,
// T14-hoisted global loads.
__global__ __launch_bounds__(256, 3) void k_attn3(
    const u16* __restrict__ gq, const u16* __restrict__ gk,
    const u16* __restrict__ wv_g,
    const float* __restrict__ lsc, const float* __restrict__ biasT,
    u16* __restrict__ wout_g) {
    __shared__ __align__(16) u16 scr[4][2048];  // per wave: v_t only

    const int tid = threadIdx.x;
    const int wave = tid >> 6, l = tid & 63, col = l & 15, quad = l >> 4;
    const int bid = blockIdx.x;                 // 4096 = 8 xcd * 512
    const int xcd = bid & 7;
    const int jl = (bid >> 3) * 4 + wave;       // 0..2047 per xcd
    const int h = jl >> 8;
    const int win = xcd * 256 + (jl & 255);
    u16* const v_t = scr[wave];  // [32 d][64 pi-slot] swz(d&7)

    u16x8 sv[4];
    #pragma unroll
    for (int it = 0; it < 4; ++it) {
        const int idx = it * 64 + l;
        const int tok = idx & 63, dblk = idx >> 6;
        sv[it] = *(const u16x8*)&wv_g[((size_t)win * 64 + tok) * 256 + h * 32 + dblk * 8];
    }
    const u16* const qbp = gq + (size_t)(win * 8 + h) * 2048;
    const u16* const kbp = gk + (size_t)(win * 8 + h) * 2048;
    bf16x8 ak[4], bq[4];
    #pragma unroll
    for (int mt = 0; mt < 4; ++mt)
        ak[mt] = *(const bf16x8*)&kbp[(mt * 16 + col) * 32 + quad * 8];
    #pragma unroll
    for (int nt = 0; nt < 4; ++nt)
        bq[nt] = *(const bf16x8*)&qbp[(nt * 16 + col) * 32 + quad * 8];

    #pragma unroll
    for (int it = 0; it < 4; ++it) {
        const int idx = it * 64 + l;
        const int tok = idx & 63, dblk = idx >> 6;
        const int g = (tok >> 5) * 4 + ((tok >> 2) & 3);
        const int jj = ((tok >> 4) & 1) * 4 + (tok & 3);
        #pragma unroll
        for (int j = 0; j < 8; ++j) {
            const int d = dblk * 8 + j;
            v_t[d * 64 + (((g ^ (d & 7)) << 3) | jj)] = sv[it][j];
        }
    }

    const f32x4 zero4 = {0.f, 0.f, 0.f, 0.f};
    f32x4 sacc[4][4];
    #pragma unroll
    for (int mt = 0; mt < 4; ++mt)
        #pragma unroll
        for (int nt = 0; nt < 4; ++nt)
            sacc[mt][nt] = __builtin_amdgcn_mfma_f32_16x16x32_bf16(ak[mt], bq[nt], zero4, 0, 0, 0);

    const float ls = expf(fminf(lsc[h], 4.6051701859880914f));
    const float* bT = biasT + h * 4096;
    #pragma unroll
    for (int nt = 0; nt < 4; ++nt) {
        const int q = nt * 16 + col;
        float v[4][4];
        float mx = -1e30f;
        #pragma unroll
        for (int mt = 0; mt < 4; ++mt)
            #pragma unroll
            for (int r = 0; r < 4; ++r) {
                v[mt][r] = sacc[mt][nt][r] * ls + bT[(mt * 16 + quad * 4 + r) * 64 + q];
                mx = fmaxf(mx, v[mt][r]);
            }
        mx = fmaxf(mx, __shfl_xor(mx, 16, 64));
        mx = fmaxf(mx, __shfl_xor(mx, 32, 64));
        float s = 0.f;
        #pragma unroll
        for (int mt = 0; mt < 4; ++mt)
            #pragma unroll
            for (int r = 0; r < 4; ++r) {
                v[mt][r] = expf(v[mt][r] - mx);
                s += v[mt][r];
            }
        s += __shfl_xor(s, 16, 64);
        s += __shfl_xor(s, 32, 64);
        const float inv = 1.0f / s;
        #pragma unroll
        for (int mt = 0; mt < 4; ++mt)
            #pragma unroll
            for (int r = 0; r < 4; ++r)
                sacc[mt][nt][r] = v[mt][r] * inv;
    }

    f32x4 oacc[2][4];
    #pragma unroll
    for (int i = 0; i < 2; ++i)
        #pragma unroll
        for (int j = 0; j < 4; ++j) oacc[i][j] = zero4;
    #pragma unroll
    for (int kk = 0; kk < 2; ++kk) {
        bf16x8 av[2];
        #pragma unroll
        for (int dt = 0; dt < 2; ++dt) {
            const int d = dt * 16 + col;
            av[dt] = *(const bf16x8*)&v_t[d * 64 + (((kk * 4 + quad) ^ (d & 7)) << 3)];
        }
        #pragma unroll
        for (int nt = 0; nt < 4; ++nt) {
            union { u16x8 u; bf16x8 b; } pk;
            #pragma unroll
            for (int j = 0; j < 4; ++j) {
                pk.u[j]     = f2b(sacc[kk * 2][nt][j]);
                pk.u[j + 4] = f2b(sacc[kk * 2 + 1][nt][j]);
            }
            #pragma unroll
            for (int dt = 0; dt < 2; ++dt)
                oacc[dt][nt] = __builtin_amdgcn_mfma_f32_16x16x32_bf16(
                    av[dt], pk.b, oacc[dt][nt], 0, 0, 0);
        }
    }
    #pragma unroll
    for (int dt = 0; dt < 2; ++dt)
        #pragma unroll
        for (int qt = 0; qt < 4; ++qt) {
            const int t = qt * 16 + col;
            u16x4 ov;
            #pragma unroll
            for (int r = 0; r < 4; ++r) ov[r] = f2b(oacc[dt][qt][r]);
            *(u16x4*)&wout_g[((size_t)win * 64 + t) * 256 + h * 32 + dt * 16 + quad * 4] = ov;
        }
}

// ---------------------------------------------------------------- proj ----
// R13 structure + sliding 3x3 register cache for the dwconv taps: each
// thread sweeps a fixed column through 8 rows, so row-taps overlap 3x ->
// loads drop 72 -> 30 per thread. Static %3 indexing via full unroll.
__global__ __launch_bounds__(256, 4) void k_proj(
    const u16* __restrict__ wout_g, const u16* __restrict__ wv_g,
    const float* __restrict__ pe_w, const float* __restrict__ pe_b,
    const u16* __restrict__ pjw, const float* __restrict__ pjb,
    float* __restrict__ out) {
    __shared__ __align__(16) u16 y_s[64 * 256];
    const int bid0 = blockIdx.x;                // 2048 = 8 xcd * 256
    const int win = (bid0 & 7) * 256 + (bid0 >> 3);
    const int b = win >> 8;
    const int h0 = ((win >> 4) & 15) * 8;
    const int w0 = (win & 15) * 8;
    const int tid = threadIdx.x;
    const int cg = tid & 31, ch = cg * 8;
    const int psub = tid >> 5;                  // column within window (fixed)
    const int gw = w0 + psub;

    float pw[9][8];
    #pragma unroll
    for (int j = 0; j < 8; ++j)
        #pragma unroll
        for (int k = 0; k < 9; ++k) pw[k][j] = pe_w[(ch + j) * 9 + k];
    float pb[8];
    #pragma unroll
    for (int j = 0; j < 8; ++j) pb[j] = pe_b[ch + j];

    bf16x8 cr[3][3];                            // sliding cache [row slot][col]
    auto load3 = [&](int rr, int slot) {
        #pragma unroll
        for (int dx = 0; dx < 3; ++dx) {
            const int ww2 = gw + dx - 1;
            bf16x8 v = {};
            if (rr >= 0 && rr < 128 && ww2 >= 0 && ww2 < 128) {
                const int nwin = b * 256 + (rr >> 3) * 16 + (ww2 >> 3);
                const int ntk = (rr & 7) * 8 + (ww2 & 7);
                v = *(const bf16x8*)&wv_g[((size_t)nwin * 64 + ntk) * 256 + ch];
            }
            cr[slot][dx] = v;
        }
    };
    load3(h0 - 1, 0);
    load3(h0,     1);
    load3(h0 + 1, 2);

    #pragma unroll
    for (int it = 0; it < 8; ++it) {
        const int p = it * 8 + psub;
        float a[8];
        {
            const bf16x8 ov = *(const bf16x8*)&wout_g[((size_t)win * 64 + p) * 256 + ch];
            #pragma unroll
            for (int j = 0; j < 8; ++j) a[j] = b2f((u16)ov[j]) + pb[j];
        }
        #pragma unroll
        for (int dy = 0; dy < 3; ++dy) {
            const int slot = (it + dy) % 3;     // compile-time after unroll
            #pragma unroll
            for (int dx = 0; dx < 3; ++dx) {
                const bf16x8 vv = cr[slot][dx];
                #pragma unroll
                for (int j = 0; j < 8; ++j)
                    a[j] += b2f((u16)vv[j]) * pw[dy * 3 + dx][j];
            }
        }
        if (it < 7) load3(h0 + it + 2, it % 3); // slide: refill freed slot
        u16x8 tmp;
        #pragma unroll
        for (int j = 0; j < 8; ++j) tmp[j] = f2b(a[j]);
        *(u16x8*)&y_s[p * 256 + (((ch >> 3) ^ (p & 7)) << 3)] = tmp;
    }
    __syncthreads();

    const int wave = tid >> 6, l = tid & 63;
    const int col = l & 15, quad = l >> 4;
    const f32x4 zero4 = {0.f, 0.f, 0.f, 0.f};
    f32x4 macc[4][4];                    // [pt(tok)][ot(och)]
    #pragma unroll
    for (int pt = 0; pt < 4; ++pt)
        #pragma unroll
        for (int ot = 0; ot < 4; ++ot) macc[pt][ot] = zero4;
    const int ob = wave * 64;
    for (int kk = 0; kk < 8; ++kk) {
        const int cb = kk * 32 + quad * 8;
        bf16x8 aw[4], by[4];
        #pragma unroll
        for (int ot = 0; ot < 4; ++ot)
            aw[ot] = *(const bf16x8*)&pjw[(size_t)(ob + ot * 16 + col) * 256 + cb];
        #pragma unroll
        for (int pt = 0; pt < 4; ++pt) {
            const int p = pt * 16 + col;
            by[pt] = *(const bf16x8*)&y_s[p * 256 + (((cb >> 3) ^ (p & 7)) << 3)];
        }
        #pragma unroll
        for (int pt = 0; pt < 4; ++pt)
            #pragma unroll
            for (int ot = 0; ot < 4; ++ot)
                macc[pt][ot] = __builtin_amdgcn_mfma_f32_16x16x32_bf16(
                    by[pt], aw[ot], macc[pt][ot], 0, 0, 0);
    }
    #pragma unroll
    for (int ot = 0; ot < 4; ++ot) {
        const int o = ob + ot * 16 + col;
        const float pbv = pjb[o];
        #pragma unroll
        for (int pt = 0; pt < 4; ++pt) {
            const int p0 = pt * 16 + quad * 4;
            float4 ov;
            ov.x = macc[pt][ot][0] + pbv;
            ov.y = macc[pt][ot][1] + pbv;
            ov.z = macc[pt][ot][2] + pbv;
            ov.w = macc[pt][ot][3] + pbv;
            *(float4*)&out[((size_t)(b * 256 + o)) * 16384 +
                           (h0 + (p0 >> 3)) * 128 + w0 + (p0 & 7)] = ov;
        }
    }
}

// -------------------------------------------------------------- launch ----
extern "C" void kernel_launch(void* const* d_in, const int* in_sizes, int n_in,
                              void* d_out, int out_size, void* d_ws, size_t ws_size,
                              hipStream_t stream) {
    const float* x    = (const float*)d_in[0];
    const float* qkvw = (const float*)d_in[1];
    const float* qkvb = (const float*)d_in[2];
    const float* pjw  = (const float*)d_in[3];
    const float* pjb  = (const float*)d_in[4];
    const float* pew  = (const float*)d_in[5];
    const float* peb  = (const float*)d_in[6];
    const float* lsc  = (const float*)d_in[7];
    const float* w1   = (const float*)d_in[8];
    const float* b1   = (const float*)d_in[9];
    const float* w2   = (const float*)d_in[10];

    char* ws = (char*)d_ws;
    u16* wv_b    = (u16*)(ws);                                    // 64 MiB
    u16* wout_b  = (u16*)(ws + (64ull << 20));                    // 64 MiB
    u16* qkvwb   = (u16*)(ws + (128ull << 20));                   // 384 KiB
    u16* pjwb    = (u16*)(ws + (128ull << 20) + 393216);          // 128 KiB
    float* biasT = (float*)(ws + (128ull << 20) + 393216 + 131072); // 128 KiB
    float* bt    = (float*)(ws + (128ull << 20) + 393216 + 262144); // 7.2 KiB

    // xt (swizzled bf16 x) lives in wout_b: dead until k_attn3 writes wout,
    // and k_qkv (its only reader) completes before k_attn3 starts.
    u16* xt = wout_b;
    // q/k scratch lives inside d_out; dead before k_proj overwrites d_out.
    u16* gq = (u16*)d_out;
    u16* gk = gq + 33554432u;

    hipLaunchKernelGGL(k_prep, dim3(768), dim3(256), 0, stream, qkvw, pjw, qkvwb, pjwb);
    hipLaunchKernelGGL(k_cpb,  dim3(1),   dim3(256), 0, stream, w1, b1, w2, bt);
    hipLaunchKernelGGL(k_bias, dim3(16),  dim3(256), 0, stream, bt, biasT);
    hipLaunchKernelGGL(k_xcvt, dim3(4096), dim3(256), 0, stream, x, xt);
    hipLaunchKernelGGL(k_qkv,  dim3(6144), dim3(256), 0, stream,
                       xt, qkvwb, qkvb, gq, gk, wv_b);
    hipLaunchKernelGGL(k_attn3, dim3(4096), dim3(256), 0, stream,
                       gq, gk, wv_b, lsc, biasT, wout_b);
    hipLaunchKernelGGL(k_proj, dim3(2048), dim3(256), 0, stream,
                       wout_b, wv_b, pew, peb, pjwb, pjb, (float*)d_out);
}

// Round 16
// 388.160 us; speedup vs baseline: 1.7616x; 1.7616x over previous
//
#include <hip/hip_runtime.h>

typedef unsigned short u16;
typedef unsigned int u32;
typedef short bf16x8 __attribute__((ext_vector_type(8)));
typedef float f32x4 __attribute__((ext_vector_type(4)));
typedef unsigned short u16x8 __attribute__((ext_vector_type(8)));
typedef unsigned short u16x4 __attribute__((ext_vector_type(4)));

#define DEVFN static __device__ __forceinline__

DEVFN u16 f2b(float f) {
    u32 u = __builtin_bit_cast(u32, f);
    u += 0x7FFFu + ((u >> 16) & 1u);
    return (u16)(u >> 16);
}
DEVFN float b2f(u16 h) {
    u32 u = ((u32)h) << 16;
    return __builtin_bit_cast(float, u);
}

typedef const __attribute__((address_space(1))) unsigned int glb_u32;
typedef __attribute__((address_space(3))) unsigned int lds_u32;
DEVFN void gload_lds16(const u16* g, u16* l) {
    __builtin_amdgcn_global_load_lds((glb_u32*)g, (lds_u32*)l, 16, 0, 0);
}

// ---------------------------------------------------------------- prep ----
__global__ void k_prep(const float* __restrict__ qkvw, const float* __restrict__ pjw,
                       u16* __restrict__ qkvwb, u16* __restrict__ pjwb) {
    int id = blockIdx.x * 256 + threadIdx.x;
    if (id < 196608) qkvwb[id] = f2b(qkvw[id]);
    if (id < 65536)  pjwb[id]  = f2b(pjw[id]);
}

__global__ void k_cpb(const float* __restrict__ w1, const float* __restrict__ b1,
                      const float* __restrict__ w2, float* __restrict__ bt) {
    int p = threadIdx.x;
    if (p >= 225) return;
    int d0 = p / 15, d1 = p % 15;
    float v0 = (float)(d0 - 7) * (8.0f / 7.0f);
    float v1 = (float)(d1 - 7) * (8.0f / 7.0f);
    float t0 = copysignf(log2f(fabsf(v0) + 1.0f) * (1.0f / 3.0f), v0);
    float t1 = copysignf(log2f(fabsf(v1) + 1.0f) * (1.0f / 3.0f), v1);
    float s[8] = {0.f, 0.f, 0.f, 0.f, 0.f, 0.f, 0.f, 0.f};
    for (int d = 0; d < 256; ++d) {
        float h = t0 * w1[2 * d] + t1 * w1[2 * d + 1] + b1[d];
        h = fmaxf(h, 0.0f);
        #pragma unroll
        for (int hh = 0; hh < 8; ++hh) s[hh] += h * w2[hh * 256 + d];
    }
    #pragma unroll
    for (int hh = 0; hh < 8; ++hh) bt[p * 8 + hh] = s[hh];
}

// TRANSPOSED bias table: biasT[h][k][q]
__global__ void k_bias(const float* __restrict__ bt, float* __restrict__ biasT) {
    int id = blockIdx.x * 256 + threadIdx.x;  // id = k*64 + q
    int kq = id >> 6, q = id & 63;
    int d0 = (q >> 3) - (kq >> 3) + 7;
    int d1 = (q & 7) - (kq & 7) + 7;
    int p = d0 * 15 + d1;
    #pragma unroll
    for (int h = 0; h < 8; ++h)
        biasT[h * 4096 + id] = 16.0f / (1.0f + expf(-bt[p * 8 + h]));
}

// ---------------------------------------------------------------- xcvt ----
// x fp32 NCHW -> bf16 in k_qkv's swizzled tile order, XCD-aligned.
__global__ __launch_bounds__(256) void k_xcvt(const float* __restrict__ x,
                                              u16* __restrict__ xt) {
    const int bid = blockIdx.x;              // 4096 = 8 xcd * 128 rowblk * 4 chunk
    const int xcd = bid & 7;
    const int i = bid >> 3;                  // 0..511
    const int rowblk = xcd * 128 + (i >> 2);
    const int c = i & 3;
    const int tid = threadIdx.x;
    const int g = tid & 7;                   // 8-ch group 0..7
    const int tseg = tid >> 3;               // 0..31
    const int tok0 = tseg * 4;
    const float* src = x + ((size_t)(rowblk >> 7) * 256 + c * 64 + g * 8) * 16384
                         + (rowblk & 127) * 128 + tok0;
    float4 v[8];
    #pragma unroll
    for (int j = 0; j < 8; ++j)
        v[j] = *(const float4*)(src + (size_t)j * 16384);
    u16x8 o0, o1, o2, o3;
    #pragma unroll
    for (int j = 0; j < 8; ++j) {
        o0[j] = f2b(v[j].x);
        o1[j] = f2b(v[j].y);
        o2[j] = f2b(v[j].z);
        o3[j] = f2b(v[j].w);
    }
    const int s0 = g ^ ((tseg ^ (tok0 + 0)) & 7);
    const int s1 = g ^ ((tseg ^ (tok0 + 1)) & 7);
    const int s2 = g ^ ((tseg ^ (tok0 + 2)) & 7);
    const int s3 = g ^ ((tseg ^ (tok0 + 3)) & 7);
    u16* dst = xt + ((size_t)rowblk * 4 + c) * 8192;
    *(u16x8*)&dst[(tok0 + 0) * 64 + (s0 << 3)] = o0;
    *(u16x8*)&dst[(tok0 + 1) * 64 + (s1 << 3)] = o1;
    *(u16x8*)&dst[(tok0 + 2) * 64 + (s2 << 3)] = o2;
    *(u16x8*)&dst[(tok0 + 3) * 64 + (s3 << 3)] = o3;
}

// ---------------------------------------------------------------- qkv -----
// gload_lds staging + weight-register dbuf. __launch_bounds__(256,3):
// (256,4)'s 128-VGPR cap spills (R4/R6/R9/R12 signature).
__global__ __launch_bounds__(256, 3) void k_qkv(
    const u16* __restrict__ xt, const u16* __restrict__ qkvw,
    const float* __restrict__ qkvb,
    u16* __restrict__ gq, u16* __restrict__ gk, u16* __restrict__ wv_g) {
    __shared__ __align__(16) u16 Xs[2][8192];  // [128 tok][64 ch] swizzled

    const int bid = blockIdx.x;                 // 6144 = 8 xcd * 128 rowblk * 6 ny
    const int xcd = bid & 7;
    const int idx = bid >> 3;
    const int ny = idx % 6;
    const int rowblk = xcd * 128 + idx / 6;
    const int b = rowblk >> 7, row = rowblk & 127;
    const int which = ny >> 1, half = ny & 1;

    const int tid = threadIdx.x;
    const int wave = tid >> 6, l = tid & 63, col = l & 15, quad = l >> 4;
    const int th = wave >> 1;
    const int oq = wave & 1;
    const int obase = half * 128 + oq * 64;

    int orow[4];
    #pragma unroll
    for (int nt = 0; nt < 4; ++nt) {
        const int oo = obase + nt * 16 + col;
        orow[nt] = (oo >> 5) * 96 + which * 32 + (oo & 31);
    }

    f32x4 acc[4][4];                            // [nt(och)][mt(tok)]
    #pragma unroll
    for (int i = 0; i < 4; ++i)
        #pragma unroll
        for (int j = 0; j < 4; ++j) acc[i][j] = f32x4{0.f, 0.f, 0.f, 0.f};

    const u16* xtb = xt + (size_t)rowblk * 32768;

    auto stage = [&](int c, int buf) {
        const u16* src = xtb + c * 8192 + wave * 2048 + l * 8;
        u16* dst = &Xs[buf][wave * 2048];
        #pragma unroll
        for (int i = 0; i < 4; ++i)
            gload_lds16(src + i * 512, dst + i * 512);
    };
    auto loadW = [&](int c, bf16x8* bw) {
        #pragma unroll
        for (int kk = 0; kk < 2; ++kk)
            #pragma unroll
            for (int nt = 0; nt < 4; ++nt)
                bw[kk * 4 + nt] = *(const bf16x8*)&qkvw[(size_t)orow[nt] * 256 +
                                                        c * 64 + kk * 32 + quad * 8];
    };
    auto gemm = [&](int buf, const bf16x8* bw) {
        #pragma unroll
        for (int kk = 0; kk < 2; ++kk) {
            const int lchunk = kk * 4 + quad;
            bf16x8 af[4];
            #pragma unroll
            for (int mt = 0; mt < 4; ++mt) {
                const int tok = th * 64 + mt * 16 + col;
                const int slot = lchunk ^ (((tok >> 2) ^ tok) & 7);
                af[mt] = *(const bf16x8*)&Xs[buf][tok * 64 + (slot << 3)];
            }
            #pragma unroll
            for (int nt = 0; nt < 4; ++nt)
                #pragma unroll
                for (int mt = 0; mt < 4; ++mt)
                    acc[nt][mt] = __builtin_amdgcn_mfma_f32_16x16x32_bf16(
                        bw[kk * 4 + nt], af[mt], acc[nt][mt], 0, 0, 0);
        }
    };

    bf16x8 bwA[8], bwB[8];
    stage(0, 0);
    loadW(0, bwA);
    __syncthreads();
    #pragma unroll
    for (int c = 0; c < 4; ++c) {
        if (c < 3) {
            stage(c + 1, (c + 1) & 1);          // async prefetch (T14)
            loadW(c + 1, (c & 1) ? bwA : bwB);  // weight prefetch
        }
        gemm(c & 1, (c & 1) ? bwB : bwA);
        __syncthreads();
    }

    // epilogue: D[och][tok]
    const int hA = obase >> 5;
    f32x4 bqv[4];
    #pragma unroll
    for (int nt = 0; nt < 4; ++nt) {
        const int oo = obase + nt * 16 + quad * 4;
        bqv[nt] = *(const f32x4*)&qkvb[(oo >> 5) * 96 + which * 32 + (oo & 31)];
    }
    #pragma unroll
    for (int mt = 0; mt < 4; ++mt) {
        const int tok = th * 64 + mt * 16 + col;
        const int win = b * 256 + (row >> 3) * 16 + (tok >> 3);
        const int tk = (row & 7) * 8 + (tok & 7);
        float v[4][4];
        #pragma unroll
        for (int nt = 0; nt < 4; ++nt)
            #pragma unroll
            for (int r = 0; r < 4; ++r)
                v[nt][r] = acc[nt][mt][r] + bqv[nt][r];
        if (which < 2) {
            float sA = 0.f, sB = 0.f;
            #pragma unroll
            for (int r = 0; r < 4; ++r) {
                sA += v[0][r] * v[0][r] + v[1][r] * v[1][r];
                sB += v[2][r] * v[2][r] + v[3][r] * v[3][r];
            }
            sA += __shfl_xor(sA, 16, 64);
            sA += __shfl_xor(sA, 32, 64);
            sB += __shfl_xor(sB, 16, 64);
            sB += __shfl_xor(sB, 32, 64);
            const float iA = 1.0f / fmaxf(sqrtf(sA), 1e-12f);
            const float iB = 1.0f / fmaxf(sqrtf(sB), 1e-12f);
            #pragma unroll
            for (int r = 0; r < 4; ++r) {
                v[0][r] *= iA; v[1][r] *= iA;
                v[2][r] *= iB; v[3][r] *= iB;
            }
        }
        #pragma unroll
        for (int nt = 0; nt < 4; ++nt) {
            u16x4 ov;
            #pragma unroll
            for (int r = 0; r < 4; ++r) ov[r] = f2b(v[nt][r]);
            if (which == 2) {
                *(u16x4*)&wv_g[((size_t)win * 64 + tk) * 256 + obase + nt * 16 + quad * 4] = ov;
            } else {
                u16* G = (which == 0) ? gq : gk;
                const int h = hA + (nt >> 1);
                const int d = (nt & 1) * 16 + quad * 4;
                *(u16x4*)&G[((size_t)(win * 8 + h) * 64 + tk) * 32 + d] = ov;
            }
        }
    }
}

// ---------------------------------------------------------------- attn ----
// S^T layout, in-register softmax, P^T from regs, XCD-aligned, T14-hoisted.
__global__ __launch_bounds__(256, 3) void k_attn3(
    const u16* __restrict__ gq, const u16* __restrict__ gk,
    const u16* __restrict__ wv_g,
    const float* __restrict__ lsc, const float* __restrict__ biasT,
    u16* __restrict__ wout_g) {
    __shared__ __align__(16) u16 scr[4][2048];  // per wave: v_t only

    const int tid = threadIdx.x;
    const int wave = tid >> 6, l = tid & 63, col = l & 15, quad = l >> 4;
    const int bid = blockIdx.x;                 // 4096 = 8 xcd * 512
    const int xcd = bid & 7;
    const int jl = (bid >> 3) * 4 + wave;       // 0..2047 per xcd
    const int h = jl >> 8;
    const int win = xcd * 256 + (jl & 255);
    u16* const v_t = scr[wave];  // [32 d][64 pi-slot] swz(d&7)

    u16x8 sv[4];
    #pragma unroll
    for (int it = 0; it < 4; ++it) {
        const int idx = it * 64 + l;
        const int tok = idx & 63, dblk = idx >> 6;
        sv[it] = *(const u16x8*)&wv_g[((size_t)win * 64 + tok) * 256 + h * 32 + dblk * 8];
    }
    const u16* const qbp = gq + (size_t)(win * 8 + h) * 2048;
    const u16* const kbp = gk + (size_t)(win * 8 + h) * 2048;
    bf16x8 ak[4], bq[4];
    #pragma unroll
    for (int mt = 0; mt < 4; ++mt)
        ak[mt] = *(const bf16x8*)&kbp[(mt * 16 + col) * 32 + quad * 8];
    #pragma unroll
    for (int nt = 0; nt < 4; ++nt)
        bq[nt] = *(const bf16x8*)&qbp[(nt * 16 + col) * 32 + quad * 8];

    #pragma unroll
    for (int it = 0; it < 4; ++it) {
        const int idx = it * 64 + l;
        const int tok = idx & 63, dblk = idx >> 6;
        const int g = (tok >> 5) * 4 + ((tok >> 2) & 3);
        const int jj = ((tok >> 4) & 1) * 4 + (tok & 3);
        #pragma unroll
        for (int j = 0; j < 8; ++j) {
            const int d = dblk * 8 + j;
            v_t[d * 64 + (((g ^ (d & 7)) << 3) | jj)] = sv[it][j];
        }
    }

    const f32x4 zero4 = {0.f, 0.f, 0.f, 0.f};
    f32x4 sacc[4][4];
    #pragma unroll
    for (int mt = 0; mt < 4; ++mt)
        #pragma unroll
        for (int nt = 0; nt < 4; ++nt)
            sacc[mt][nt] = __builtin_amdgcn_mfma_f32_16x16x32_bf16(ak[mt], bq[nt], zero4, 0, 0, 0);

    const float ls = expf(fminf(lsc[h], 4.6051701859880914f));
    const float* bT = biasT + h * 4096;
    #pragma unroll
    for (int nt = 0; nt < 4; ++nt) {
        const int q = nt * 16 + col;
        float v[4][4];
        float mx = -1e30f;
        #pragma unroll
        for (int mt = 0; mt < 4; ++mt)
            #pragma unroll
            for (int r = 0; r < 4; ++r) {
                v[mt][r] = sacc[mt][nt][r] * ls + bT[(mt * 16 + quad * 4 + r) * 64 + q];
                mx = fmaxf(mx, v[mt][r]);
            }
        mx = fmaxf(mx, __shfl_xor(mx, 16, 64));
        mx = fmaxf(mx, __shfl_xor(mx, 32, 64));
        float s = 0.f;
        #pragma unroll
        for (int mt = 0; mt < 4; ++mt)
            #pragma unroll
            for (int r = 0; r < 4; ++r) {
                v[mt][r] = expf(v[mt][r] - mx);
                s += v[mt][r];
            }
        s += __shfl_xor(s, 16, 64);
        s += __shfl_xor(s, 32, 64);
        const float inv = 1.0f / s;
        #pragma unroll
        for (int mt = 0; mt < 4; ++mt)
            #pragma unroll
            for (int r = 0; r < 4; ++r)
                sacc[mt][nt][r] = v[mt][r] * inv;
    }

    f32x4 oacc[2][4];
    #pragma unroll
    for (int i = 0; i < 2; ++i)
        #pragma unroll
        for (int j = 0; j < 4; ++j) oacc[i][j] = zero4;
    #pragma unroll
    for (int kk = 0; kk < 2; ++kk) {
        bf16x8 av[2];
        #pragma unroll
        for (int dt = 0; dt < 2; ++dt) {
            const int d = dt * 16 + col;
            av[dt] = *(const bf16x8*)&v_t[d * 64 + (((kk * 4 + quad) ^ (d & 7)) << 3)];
        }
        #pragma unroll
        for (int nt = 0; nt < 4; ++nt) {
            union { u16x8 u; bf16x8 b; } pk;
            #pragma unroll
            for (int j = 0; j < 4; ++j) {
                pk.u[j]     = f2b(sacc[kk * 2][nt][j]);
                pk.u[j + 4] = f2b(sacc[kk * 2 + 1][nt][j]);
            }
            #pragma unroll
            for (int dt = 0; dt < 2; ++dt)
                oacc[dt][nt] = __builtin_amdgcn_mfma_f32_16x16x32_bf16(
                    av[dt], pk.b, oacc[dt][nt], 0, 0, 0);
        }
    }
    #pragma unroll
    for (int dt = 0; dt < 2; ++dt)
        #pragma unroll
        for (int qt = 0; qt < 4; ++qt) {
            const int t = qt * 16 + col;
            u16x4 ov;
            #pragma unroll
            for (int r = 0; r < 4; ++r) ov[r] = f2b(oacc[dt][qt][r]);
            *(u16x4*)&wout_g[((size_t)win * 64 + t) * 256 + h * 32 + dt * 16 + quad * 4] = ov;
        }
}

// ---------------------------------------------------------------- proj ----
// R13 verbatim: operand-swapped GEMM, float4 stores, XCD-aligned win map.
__global__ __launch_bounds__(256, 4) void k_proj(
    const u16* __restrict__ wout_g, const u16* __restrict__ wv_g,
    const float* __restrict__ pe_w, const float* __restrict__ pe_b,
    const u16* __restrict__ pjw, const float* __restrict__ pjb,
    float* __restrict__ out) {
    __shared__ __align__(16) u16 y_s[64 * 256];
    const int bid0 = blockIdx.x;                // 2048 = 8 xcd * 256
    const int win = (bid0 & 7) * 256 + (bid0 >> 3);
    const int b = win >> 8;
    const int h0 = ((win >> 4) & 15) * 8;
    const int w0 = (win & 15) * 8;
    const int tid = threadIdx.x;
    const int cg = tid & 31, ch = cg * 8;
    const int psub = tid >> 5;

    float pw[9][8];
    #pragma unroll
    for (int j = 0; j < 8; ++j)
        #pragma unroll
        for (int k = 0; k < 9; ++k) pw[k][j] = pe_w[(ch + j) * 9 + k];
    float pb[8];
    #pragma unroll
    for (int j = 0; j < 8; ++j) pb[j] = pe_b[ch + j];

    for (int it = 0; it < 8; ++it) {
        const int p = it * 8 + psub;
        const int gh = h0 + (p >> 3), gw = w0 + (p & 7);
        float a[8];
        {
            const bf16x8 ov = *(const bf16x8*)&wout_g[((size_t)win * 64 + p) * 256 + ch];
            #pragma unroll
            for (int j = 0; j < 8; ++j) a[j] = b2f((u16)ov[j]) + pb[j];
        }
        #pragma unroll
        for (int dy = -1; dy <= 1; ++dy)
            #pragma unroll
            for (int dx = -1; dx <= 1; ++dx) {
                const int hh = gh + dy, ww2 = gw + dx;
                if (hh < 0 || hh >= 128 || ww2 < 0 || ww2 >= 128) continue;
                const int nwin = b * 256 + (hh >> 3) * 16 + (ww2 >> 3);
                const int ntk = (hh & 7) * 8 + (ww2 & 7);
                const bf16x8 vv = *(const bf16x8*)&wv_g[((size_t)nwin * 64 + ntk) * 256 + ch];
                const int k = (dy + 1) * 3 + (dx + 1);
                #pragma unroll
                for (int j = 0; j < 8; ++j) a[j] += b2f((u16)vv[j]) * pw[k][j];
            }
        u16x8 tmp;
        #pragma unroll
        for (int j = 0; j < 8; ++j) tmp[j] = f2b(a[j]);
        *(u16x8*)&y_s[p * 256 + (((ch >> 3) ^ (p & 7)) << 3)] = tmp;
    }
    __syncthreads();

    const int wave = tid >> 6, l = tid & 63;
    const int col = l & 15, quad = l >> 4;
    const f32x4 zero4 = {0.f, 0.f, 0.f, 0.f};
    f32x4 macc[4][4];                    // [pt(tok)][ot(och)]
    #pragma unroll
    for (int pt = 0; pt < 4; ++pt)
        #pragma unroll
        for (int ot = 0; ot < 4; ++ot) macc[pt][ot] = zero4;
    const int ob = wave * 64;
    for (int kk = 0; kk < 8; ++kk) {
        const int cb = kk * 32 + quad * 8;
        bf16x8 aw[4], by[4];
        #pragma unroll
        for (int ot = 0; ot < 4; ++ot)
            aw[ot] = *(const bf16x8*)&pjw[(size_t)(ob + ot * 16 + col) * 256 + cb];
        #pragma unroll
        for (int pt = 0; pt < 4; ++pt) {
            const int p = pt * 16 + col;
            by[pt] = *(const bf16x8*)&y_s[p * 256 + (((cb >> 3) ^ (p & 7)) << 3)];
        }
        #pragma unroll
        for (int pt = 0; pt < 4; ++pt)
            #pragma unroll
            for (int ot = 0; ot < 4; ++ot)
                macc[pt][ot] = __builtin_amdgcn_mfma_f32_16x16x32_bf16(
                    by[pt], aw[ot], macc[pt][ot], 0, 0, 0);
    }
    #pragma unroll
    for (int ot = 0; ot < 4; ++ot) {
        const int o = ob + ot * 16 + col;
        const float pbv = pjb[o];
        #pragma unroll
        for (int pt = 0; pt < 4; ++pt) {
            const int p0 = pt * 16 + quad * 4;
            float4 ov;
            ov.x = macc[pt][ot][0] + pbv;
            ov.y = macc[pt][ot][1] + pbv;
            ov.z = macc[pt][ot][2] + pbv;
            ov.w = macc[pt][ot][3] + pbv;
            *(float4*)&out[((size_t)(b * 256 + o)) * 16384 +
                           (h0 + (p0 >> 3)) * 128 + w0 + (p0 & 7)] = ov;
        }
    }
}

// -------------------------------------------------------------- launch ----
extern "C" void kernel_launch(void* const* d_in, const int* in_sizes, int n_in,
                              void* d_out, int out_size, void* d_ws, size_t ws_size,
                              hipStream_t stream) {
    const float* x    = (const float*)d_in[0];
    const float* qkvw = (const float*)d_in[1];
    const float* qkvb = (const float*)d_in[2];
    const float* pjw  = (const float*)d_in[3];
    const float* pjb  = (const float*)d_in[4];
    const float* pew  = (const float*)d_in[5];
    const float* peb  = (const float*)d_in[6];
    const float* lsc  = (const float*)d_in[7];
    const float* w1   = (const float*)d_in[8];
    const float* b1   = (const float*)d_in[9];
    const float* w2   = (const float*)d_in[10];

    char* ws = (char*)d_ws;
    u16* wv_b    = (u16*)(ws);                                    // 64 MiB
    u16* wout_b  = (u16*)(ws + (64ull << 20));                    // 64 MiB
    u16* qkvwb   = (u16*)(ws + (128ull << 20));                   // 384 KiB
    u16* pjwb    = (u16*)(ws + (128ull << 20) + 393216);          // 128 KiB
    float* biasT = (float*)(ws + (128ull << 20) + 393216 + 131072); // 128 KiB
    float* bt    = (float*)(ws + (128ull << 20) + 393216 + 262144); // 7.2 KiB

    // xt (swizzled bf16 x) lives in wout_b: dead until k_attn3 writes wout,
    // and k_qkv (its only reader) completes before k_attn3 starts.
    u16* xt = wout_b;
    // q/k scratch lives inside d_out; dead before k_proj overwrites d_out.
    u16* gq = (u16*)d_out;
    u16* gk = gq + 33554432u;

    hipLaunchKernelGGL(k_prep, dim3(768), dim3(256), 0, stream, qkvw, pjw, qkvwb, pjwb);
    hipLaunchKernelGGL(k_cpb,  dim3(1),   dim3(256), 0, stream, w1, b1, w2, bt);
    hipLaunchKernelGGL(k_bias, dim3(16),  dim3(256), 0, stream, bt, biasT);
    hipLaunchKernelGGL(k_xcvt, dim3(4096), dim3(256), 0, stream, x, xt);
    hipLaunchKernelGGL(k_qkv,  dim3(6144), dim3(256), 0, stream,
                       xt, qkvwb, qkvb, gq, gk, wv_b);
    hipLaunchKernelGGL(k_attn3, dim3(4096), dim3(256), 0, stream,
                       gq, gk, wv_b, lsc, biasT, wout_b);
    hipLaunchKernelGGL(k_proj, dim3(2048), dim3(256), 0, stream,
                       wout_b, wv_b, pew, peb, pjwb, pjb, (float*)d_out);
}

// Round 17
// 363.147 us; speedup vs baseline: 1.8829x; 1.0689x over previous
//
#include <hip/hip_runtime.h>

typedef unsigned short u16;
typedef unsigned int u32;
typedef short bf16x8 __attribute__((ext_vector_type(8)));
typedef float f32x4 __attribute__((ext_vector_type(4)));
typedef unsigned short u16x8 __attribute__((ext_vector_type(8)));
typedef unsigned short u16x4 __attribute__((ext_vector_type(4)));

#define DEVFN static __device__ __forceinline__

DEVFN u16 f2b(float f) {
    u32 u = __builtin_bit_cast(u32, f);
    u += 0x7FFFu + ((u >> 16) & 1u);
    return (u16)(u >> 16);
}
DEVFN float b2f(u16 h) {
    u32 u = ((u32)h) << 16;
    return __builtin_bit_cast(float, u);
}

typedef const __attribute__((address_space(1))) unsigned int glb_u32;
typedef __attribute__((address_space(3))) unsigned int lds_u32;
DEVFN void gload_lds16(const u16* g, u16* l) {
    __builtin_amdgcn_global_load_lds((glb_u32*)g, (lds_u32*)l, 16, 0, 0);
}

// ---------------------------------------------------------------- prep ----
__global__ void k_prep(const float* __restrict__ qkvw, const float* __restrict__ pjw,
                       u16* __restrict__ qkvwb, u16* __restrict__ pjwb) {
    int id = blockIdx.x * 256 + threadIdx.x;
    if (id < 196608) qkvwb[id] = f2b(qkvw[id]);
    if (id < 65536)  pjwb[id]  = f2b(pjw[id]);
}

// Parallel CPB MLP: block = table position p (225 blocks), thread = hidden dim d.
// Replaces the single-block 256-iteration serial chain (~10-25us idle GPU).
__global__ __launch_bounds__(256) void k_cpb(
    const float* __restrict__ w1, const float* __restrict__ b1,
    const float* __restrict__ w2, float* __restrict__ bt) {
    __shared__ float red[4][8];
    const int p = blockIdx.x;       // 0..224
    const int d = threadIdx.x;      // 0..255
    const int d0 = p / 15, d1 = p % 15;
    const float v0 = (float)(d0 - 7) * (8.0f / 7.0f);
    const float v1 = (float)(d1 - 7) * (8.0f / 7.0f);
    const float t0 = copysignf(log2f(fabsf(v0) + 1.0f) * (1.0f / 3.0f), v0);
    const float t1 = copysignf(log2f(fabsf(v1) + 1.0f) * (1.0f / 3.0f), v1);
    const float h = fmaxf(t0 * w1[2 * d] + t1 * w1[2 * d + 1] + b1[d], 0.0f);
    float s[8];
    #pragma unroll
    for (int hh = 0; hh < 8; ++hh) s[hh] = h * w2[hh * 256 + d];
    #pragma unroll
    for (int m = 1; m < 64; m <<= 1)
        #pragma unroll
        for (int hh = 0; hh < 8; ++hh) s[hh] += __shfl_xor(s[hh], m, 64);
    const int wave = d >> 6, l = d & 63;
    if (l == 0)
        #pragma unroll
        for (int hh = 0; hh < 8; ++hh) red[wave][hh] = s[hh];
    __syncthreads();
    if (d < 8)
        bt[p * 8 + d] = red[0][d] + red[1][d] + red[2][d] + red[3][d];
}

// TRANSPOSED bias table: biasT[h][k][q]
__global__ void k_bias(const float* __restrict__ bt, float* __restrict__ biasT) {
    int id = blockIdx.x * 256 + threadIdx.x;  // id = k*64 + q
    int kq = id >> 6, q = id & 63;
    int d0 = (q >> 3) - (kq >> 3) + 7;
    int d1 = (q & 7) - (kq & 7) + 7;
    int p = d0 * 15 + d1;
    #pragma unroll
    for (int h = 0; h < 8; ++h)
        biasT[h * 4096 + id] = 16.0f / (1.0f + expf(-bt[p * 8 + h]));
}

// ---------------------------------------------------------------- xcvt ----
// x fp32 NCHW -> bf16 in k_qkv's swizzled tile order, XCD-aligned.
__global__ __launch_bounds__(256) void k_xcvt(const float* __restrict__ x,
                                              u16* __restrict__ xt) {
    const int bid = blockIdx.x;              // 4096 = 8 xcd * 128 rowblk * 4 chunk
    const int xcd = bid & 7;
    const int i = bid >> 3;                  // 0..511
    const int rowblk = xcd * 128 + (i >> 2);
    const int c = i & 3;
    const int tid = threadIdx.x;
    const int g = tid & 7;                   // 8-ch group 0..7
    const int tseg = tid >> 3;               // 0..31
    const int tok0 = tseg * 4;
    const float* src = x + ((size_t)(rowblk >> 7) * 256 + c * 64 + g * 8) * 16384
                         + (rowblk & 127) * 128 + tok0;
    float4 v[8];
    #pragma unroll
    for (int j = 0; j < 8; ++j)
        v[j] = *(const float4*)(src + (size_t)j * 16384);
    u16x8 o0, o1, o2, o3;
    #pragma unroll
    for (int j = 0; j < 8; ++j) {
        o0[j] = f2b(v[j].x);
        o1[j] = f2b(v[j].y);
        o2[j] = f2b(v[j].z);
        o3[j] = f2b(v[j].w);
    }
    const int s0 = g ^ ((tseg ^ (tok0 + 0)) & 7);
    const int s1 = g ^ ((tseg ^ (tok0 + 1)) & 7);
    const int s2 = g ^ ((tseg ^ (tok0 + 2)) & 7);
    const int s3 = g ^ ((tseg ^ (tok0 + 3)) & 7);
    u16* dst = xt + ((size_t)rowblk * 4 + c) * 8192;
    *(u16x8*)&dst[(tok0 + 0) * 64 + (s0 << 3)] = o0;
    *(u16x8*)&dst[(tok0 + 1) * 64 + (s1 << 3)] = o1;
    *(u16x8*)&dst[(tok0 + 2) * 64 + (s2 << 3)] = o2;
    *(u16x8*)&dst[(tok0 + 3) * 64 + (s3 << 3)] = o3;
}

// ---------------------------------------------------------------- qkv -----
// gload_lds staging + weight-register dbuf. __launch_bounds__(256,3):
// (256,4)'s 128-VGPR cap spills (R4/R6/R9/R12 signature).
__global__ __launch_bounds__(256, 3) void k_qkv(
    const u16* __restrict__ xt, const u16* __restrict__ qkvw,
    const float* __restrict__ qkvb,
    u16* __restrict__ gq, u16* __restrict__ gk, u16* __restrict__ wv_g) {
    __shared__ __align__(16) u16 Xs[2][8192];  // [128 tok][64 ch] swizzled

    const int bid = blockIdx.x;                 // 6144 = 8 xcd * 128 rowblk * 6 ny
    const int xcd = bid & 7;
    const int idx = bid >> 3;
    const int ny = idx % 6;
    const int rowblk = xcd * 128 + idx / 6;
    const int b = rowblk >> 7, row = rowblk & 127;
    const int which = ny >> 1, half = ny & 1;

    const int tid = threadIdx.x;
    const int wave = tid >> 6, l = tid & 63, col = l & 15, quad = l >> 4;
    const int th = wave >> 1;
    const int oq = wave & 1;
    const int obase = half * 128 + oq * 64;

    int orow[4];
    #pragma unroll
    for (int nt = 0; nt < 4; ++nt) {
        const int oo = obase + nt * 16 + col;
        orow[nt] = (oo >> 5) * 96 + which * 32 + (oo & 31);
    }

    f32x4 acc[4][4];                            // [nt(och)][mt(tok)]
    #pragma unroll
    for (int i = 0; i < 4; ++i)
        #pragma unroll
        for (int j = 0; j < 4; ++j) acc[i][j] = f32x4{0.f, 0.f, 0.f, 0.f};

    const u16* xtb = xt + (size_t)rowblk * 32768;

    auto stage = [&](int c, int buf) {
        const u16* src = xtb + c * 8192 + wave * 2048 + l * 8;
        u16* dst = &Xs[buf][wave * 2048];
        #pragma unroll
        for (int i = 0; i < 4; ++i)
            gload_lds16(src + i * 512, dst + i * 512);
    };
    auto loadW = [&](int c, bf16x8* bw) {
        #pragma unroll
        for (int kk = 0; kk < 2; ++kk)
            #pragma unroll
            for (int nt = 0; nt < 4; ++nt)
                bw[kk * 4 + nt] = *(const bf16x8*)&qkvw[(size_t)orow[nt] * 256 +
                                                        c * 64 + kk * 32 + quad * 8];
    };
    auto gemm = [&](int buf, const bf16x8* bw) {
        #pragma unroll
        for (int kk = 0; kk < 2; ++kk) {
            const int lchunk = kk * 4 + quad;
            bf16x8 af[4];
            #pragma unroll
            for (int mt = 0; mt < 4; ++mt) {
                const int tok = th * 64 + mt * 16 + col;
                const int slot = lchunk ^ (((tok >> 2) ^ tok) & 7);
                af[mt] = *(const bf16x8*)&Xs[buf][tok * 64 + (slot << 3)];
            }
            #pragma unroll
            for (int nt = 0; nt < 4; ++nt)
                #pragma unroll
                for (int mt = 0; mt < 4; ++mt)
                    acc[nt][mt] = __builtin_amdgcn_mfma_f32_16x16x32_bf16(
                        bw[kk * 4 + nt], af[mt], acc[nt][mt], 0, 0, 0);
        }
    };

    bf16x8 bwA[8], bwB[8];
    stage(0, 0);
    loadW(0, bwA);
    __syncthreads();
    #pragma unroll
    for (int c = 0; c < 4; ++c) {
        if (c < 3) {
            stage(c + 1, (c + 1) & 1);          // async prefetch (T14)
            loadW(c + 1, (c & 1) ? bwA : bwB);  // weight prefetch
        }
        gemm(c & 1, (c & 1) ? bwB : bwA);
        __syncthreads();
    }

    // epilogue: D[och][tok]
    const int hA = obase >> 5;
    f32x4 bqv[4];
    #pragma unroll
    for (int nt = 0; nt < 4; ++nt) {
        const int oo = obase + nt * 16 + quad * 4;
        bqv[nt] = *(const f32x4*)&qkvb[(oo >> 5) * 96 + which * 32 + (oo & 31)];
    }
    #pragma unroll
    for (int mt = 0; mt < 4; ++mt) {
        const int tok = th * 64 + mt * 16 + col;
        const int win = b * 256 + (row >> 3) * 16 + (tok >> 3);
        const int tk = (row & 7) * 8 + (tok & 7);
        float v[4][4];
        #pragma unroll
        for (int nt = 0; nt < 4; ++nt)
            #pragma unroll
            for (int r = 0; r < 4; ++r)
                v[nt][r] = acc[nt][mt][r] + bqv[nt][r];
        if (which < 2) {
            float sA = 0.f, sB = 0.f;
            #pragma unroll
            for (int r = 0; r < 4; ++r) {
                sA += v[0][r] * v[0][r] + v[1][r] * v[1][r];
                sB += v[2][r] * v[2][r] + v[3][r] * v[3][r];
            }
            sA += __shfl_xor(sA, 16, 64);
            sA += __shfl_xor(sA, 32, 64);
            sB += __shfl_xor(sB, 16, 64);
            sB += __shfl_xor(sB, 32, 64);
            const float iA = 1.0f / fmaxf(sqrtf(sA), 1e-12f);
            const float iB = 1.0f / fmaxf(sqrtf(sB), 1e-12f);
            #pragma unroll
            for (int r = 0; r < 4; ++r) {
                v[0][r] *= iA; v[1][r] *= iA;
                v[2][r] *= iB; v[3][r] *= iB;
            }
        }
        #pragma unroll
        for (int nt = 0; nt < 4; ++nt) {
            u16x4 ov;
            #pragma unroll
            for (int r = 0; r < 4; ++r) ov[r] = f2b(v[nt][r]);
            if (which == 2) {
                *(u16x4*)&wv_g[((size_t)win * 64 + tk) * 256 + obase + nt * 16 + quad * 4] = ov;
            } else {
                u16* G = (which == 0) ? gq : gk;
                const int h = hA + (nt >> 1);
                const int d = (nt & 1) * 16 + quad * 4;
                *(u16x4*)&G[((size_t)(win * 8 + h) * 64 + tk) * 32 + d] = ov;
            }
        }
    }
}

// ---------------------------------------------------------------- attn ----
// S^T layout, in-register softmax, P^T from regs, XCD-aligned, T14-hoisted.
__global__ __launch_bounds__(256, 3) void k_attn3(
    const u16* __restrict__ gq, const u16* __restrict__ gk,
    const u16* __restrict__ wv_g,
    const float* __restrict__ lsc, const float* __restrict__ biasT,
    u16* __restrict__ wout_g) {
    __shared__ __align__(16) u16 scr[4][2048];  // per wave: v_t only

    const int tid = threadIdx.x;
    const int wave = tid >> 6, l = tid & 63, col = l & 15, quad = l >> 4;
    const int bid = blockIdx.x;                 // 4096 = 8 xcd * 512
    const int xcd = bid & 7;
    const int jl = (bid >> 3) * 4 + wave;       // 0..2047 per xcd
    const int h = jl >> 8;
    const int win = xcd * 256 + (jl & 255);
    u16* const v_t = scr[wave];  // [32 d][64 pi-slot] swz(d&7)

    u16x8 sv[4];
    #pragma unroll
    for (int it = 0; it < 4; ++it) {
        const int idx = it * 64 + l;
        const int tok = idx & 63, dblk = idx >> 6;
        sv[it] = *(const u16x8*)&wv_g[((size_t)win * 64 + tok) * 256 + h * 32 + dblk * 8];
    }
    const u16* const qbp = gq + (size_t)(win * 8 + h) * 2048;
    const u16* const kbp = gk + (size_t)(win * 8 + h) * 2048;
    bf16x8 ak[4], bq[4];
    #pragma unroll
    for (int mt = 0; mt < 4; ++mt)
        ak[mt] = *(const bf16x8*)&kbp[(mt * 16 + col) * 32 + quad * 8];
    #pragma unroll
    for (int nt = 0; nt < 4; ++nt)
        bq[nt] = *(const bf16x8*)&qbp[(nt * 16 + col) * 32 + quad * 8];

    #pragma unroll
    for (int it = 0; it < 4; ++it) {
        const int idx = it * 64 + l;
        const int tok = idx & 63, dblk = idx >> 6;
        const int g = (tok >> 5) * 4 + ((tok >> 2) & 3);
        const int jj = ((tok >> 4) & 1) * 4 + (tok & 3);
        #pragma unroll
        for (int j = 0; j < 8; ++j) {
            const int d = dblk * 8 + j;
            v_t[d * 64 + (((g ^ (d & 7)) << 3) | jj)] = sv[it][j];
        }
    }

    const f32x4 zero4 = {0.f, 0.f, 0.f, 0.f};
    f32x4 sacc[4][4];
    #pragma unroll
    for (int mt = 0; mt < 4; ++mt)
        #pragma unroll
        for (int nt = 0; nt < 4; ++nt)
            sacc[mt][nt] = __builtin_amdgcn_mfma_f32_16x16x32_bf16(ak[mt], bq[nt], zero4, 0, 0, 0);

    const float ls = expf(fminf(lsc[h], 4.6051701859880914f));
    const float* bT = biasT + h * 4096;
    #pragma unroll
    for (int nt = 0; nt < 4; ++nt) {
        const int q = nt * 16 + col;
        float v[4][4];
        float mx = -1e30f;
        #pragma unroll
        for (int mt = 0; mt < 4; ++mt)
            #pragma unroll
            for (int r = 0; r < 4; ++r) {
                v[mt][r] = sacc[mt][nt][r] * ls + bT[(mt * 16 + quad * 4 + r) * 64 + q];
                mx = fmaxf(mx, v[mt][r]);
            }
        mx = fmaxf(mx, __shfl_xor(mx, 16, 64));
        mx = fmaxf(mx, __shfl_xor(mx, 32, 64));
        float s = 0.f;
        #pragma unroll
        for (int mt = 0; mt < 4; ++mt)
            #pragma unroll
            for (int r = 0; r < 4; ++r) {
                v[mt][r] = expf(v[mt][r] - mx);
                s += v[mt][r];
            }
        s += __shfl_xor(s, 16, 64);
        s += __shfl_xor(s, 32, 64);
        const float inv = 1.0f / s;
        #pragma unroll
        for (int mt = 0; mt < 4; ++mt)
            #pragma unroll
            for (int r = 0; r < 4; ++r)
                sacc[mt][nt][r] = v[mt][r] * inv;
    }

    f32x4 oacc[2][4];
    #pragma unroll
    for (int i = 0; i < 2; ++i)
        #pragma unroll
        for (int j = 0; j < 4; ++j) oacc[i][j] = zero4;
    #pragma unroll
    for (int kk = 0; kk < 2; ++kk) {
        bf16x8 av[2];
        #pragma unroll
        for (int dt = 0; dt < 2; ++dt) {
            const int d = dt * 16 + col;
            av[dt] = *(const bf16x8*)&v_t[d * 64 + (((kk * 4 + quad) ^ (d & 7)) << 3)];
        }
        #pragma unroll
        for (int nt = 0; nt < 4; ++nt) {
            union { u16x8 u; bf16x8 b; } pk;
            #pragma unroll
            for (int j = 0; j < 4; ++j) {
                pk.u[j]     = f2b(sacc[kk * 2][nt][j]);
                pk.u[j + 4] = f2b(sacc[kk * 2 + 1][nt][j]);
            }
            #pragma unroll
            for (int dt = 0; dt < 2; ++dt)
                oacc[dt][nt] = __builtin_amdgcn_mfma_f32_16x16x32_bf16(
                    av[dt], pk.b, oacc[dt][nt], 0, 0, 0);
        }
    }
    #pragma unroll
    for (int dt = 0; dt < 2; ++dt)
        #pragma unroll
        for (int qt = 0; qt < 4; ++qt) {
            const int t = qt * 16 + col;
            u16x4 ov;
            #pragma unroll
            for (int r = 0; r < 4; ++r) ov[r] = f2b(oacc[dt][qt][r]);
            *(u16x4*)&wout_g[((size_t)win * 64 + t) * 256 + h * 32 + dt * 16 + quad * 4] = ov;
        }
}

// ---------------------------------------------------------------- proj ----
// R13 verbatim: operand-swapped GEMM, float4 stores, XCD-aligned win map.
__global__ __launch_bounds__(256, 4) void k_proj(
    const u16* __restrict__ wout_g, const u16* __restrict__ wv_g,
    const float* __restrict__ pe_w, const float* __restrict__ pe_b,
    const u16* __restrict__ pjw, const float* __restrict__ pjb,
    float* __restrict__ out) {
    __shared__ __align__(16) u16 y_s[64 * 256];
    const int bid0 = blockIdx.x;                // 2048 = 8 xcd * 256
    const int win = (bid0 & 7) * 256 + (bid0 >> 3);
    const int b = win >> 8;
    const int h0 = ((win >> 4) & 15) * 8;
    const int w0 = (win & 15) * 8;
    const int tid = threadIdx.x;
    const int cg = tid & 31, ch = cg * 8;
    const int psub = tid >> 5;

    float pw[9][8];
    #pragma unroll
    for (int j = 0; j < 8; ++j)
        #pragma unroll
        for (int k = 0; k < 9; ++k) pw[k][j] = pe_w[(ch + j) * 9 + k];
    float pb[8];
    #pragma unroll
    for (int j = 0; j < 8; ++j) pb[j] = pe_b[ch + j];

    for (int it = 0; it < 8; ++it) {
        const int p = it * 8 + psub;
        const int gh = h0 + (p >> 3), gw = w0 + (p & 7);
        float a[8];
        {
            const bf16x8 ov = *(const bf16x8*)&wout_g[((size_t)win * 64 + p) * 256 + ch];
            #pragma unroll
            for (int j = 0; j < 8; ++j) a[j] = b2f((u16)ov[j]) + pb[j];
        }
        #pragma unroll
        for (int dy = -1; dy <= 1; ++dy)
            #pragma unroll
            for (int dx = -1; dx <= 1; ++dx) {
                const int hh = gh + dy, ww2 = gw + dx;
                if (hh < 0 || hh >= 128 || ww2 < 0 || ww2 >= 128) continue;
                const int nwin = b * 256 + (hh >> 3) * 16 + (ww2 >> 3);
                const int ntk = (hh & 7) * 8 + (ww2 & 7);
                const bf16x8 vv = *(const bf16x8*)&wv_g[((size_t)nwin * 64 + ntk) * 256 + ch];
                const int k = (dy + 1) * 3 + (dx + 1);
                #pragma unroll
                for (int j = 0; j < 8; ++j) a[j] += b2f((u16)vv[j]) * pw[k][j];
            }
        u16x8 tmp;
        #pragma unroll
        for (int j = 0; j < 8; ++j) tmp[j] = f2b(a[j]);
        *(u16x8*)&y_s[p * 256 + (((ch >> 3) ^ (p & 7)) << 3)] = tmp;
    }
    __syncthreads();

    const int wave = tid >> 6, l = tid & 63;
    const int col = l & 15, quad = l >> 4;
    const f32x4 zero4 = {0.f, 0.f, 0.f, 0.f};
    f32x4 macc[4][4];                    // [pt(tok)][ot(och)]
    #pragma unroll
    for (int pt = 0; pt < 4; ++pt)
        #pragma unroll
        for (int ot = 0; ot < 4; ++ot) macc[pt][ot] = zero4;
    const int ob = wave * 64;
    for (int kk = 0; kk < 8; ++kk) {
        const int cb = kk * 32 + quad * 8;
        bf16x8 aw[4], by[4];
        #pragma unroll
        for (int ot = 0; ot < 4; ++ot)
            aw[ot] = *(const bf16x8*)&pjw[(size_t)(ob + ot * 16 + col) * 256 + cb];
        #pragma unroll
        for (int pt = 0; pt < 4; ++pt) {
            const int p = pt * 16 + col;
            by[pt] = *(const bf16x8*)&y_s[p * 256 + (((cb >> 3) ^ (p & 7)) << 3)];
        }
        #pragma unroll
        for (int pt = 0; pt < 4; ++pt)
            #pragma unroll
            for (int ot = 0; ot < 4; ++ot)
                macc[pt][ot] = __builtin_amdgcn_mfma_f32_16x16x32_bf16(
                    by[pt], aw[ot], macc[pt][ot], 0, 0, 0);
    }
    #pragma unroll
    for (int ot = 0; ot < 4; ++ot) {
        const int o = ob + ot * 16 + col;
        const float pbv = pjb[o];
        #pragma unroll
        for (int pt = 0; pt < 4; ++pt) {
            const int p0 = pt * 16 + quad * 4;
            float4 ov;
            ov.x = macc[pt][ot][0] + pbv;
            ov.y = macc[pt][ot][1] + pbv;
            ov.z = macc[pt][ot][2] + pbv;
            ov.w = macc[pt][ot][3] + pbv;
            *(float4*)&out[((size_t)(b * 256 + o)) * 16384 +
                           (h0 + (p0 >> 3)) * 128 + w0 + (p0 & 7)] = ov;
        }
    }
}

// -------------------------------------------------------------- launch ----
extern "C" void kernel_launch(void* const* d_in, const int* in_sizes, int n_in,
                              void* d_out, int out_size, void* d_ws, size_t ws_size,
                              hipStream_t stream) {
    const float* x    = (const float*)d_in[0];
    const float* qkvw = (const float*)d_in[1];
    const float* qkvb = (const float*)d_in[2];
    const float* pjw  = (const float*)d_in[3];
    const float* pjb  = (const float*)d_in[4];
    const float* pew  = (const float*)d_in[5];
    const float* peb  = (const float*)d_in[6];
    const float* lsc  = (const float*)d_in[7];
    const float* w1   = (const float*)d_in[8];
    const float* b1   = (const float*)d_in[9];
    const float* w2   = (const float*)d_in[10];

    char* ws = (char*)d_ws;
    u16* wv_b    = (u16*)(ws);                                    // 64 MiB
    u16* wout_b  = (u16*)(ws + (64ull << 20));                    // 64 MiB
    u16* qkvwb   = (u16*)(ws + (128ull << 20));                   // 384 KiB
    u16* pjwb    = (u16*)(ws + (128ull << 20) + 393216);          // 128 KiB
    float* biasT = (float*)(ws + (128ull << 20) + 393216 + 131072); // 128 KiB
    float* bt    = (float*)(ws + (128ull << 20) + 393216 + 262144); // 7.2 KiB

    // xt (swizzled bf16 x) lives in wout_b: dead until k_attn3 writes wout,
    // and k_qkv (its only reader) completes before k_attn3 starts.
    u16* xt = wout_b;
    // q/k scratch lives inside d_out; dead before k_proj overwrites d_out.
    u16* gq = (u16*)d_out;
    u16* gk = gq + 33554432u;

    hipLaunchKernelGGL(k_prep, dim3(768), dim3(256), 0, stream, qkvw, pjw, qkvwb, pjwb);
    hipLaunchKernelGGL(k_cpb,  dim3(225), dim3(256), 0, stream, w1, b1, w2, bt);
    hipLaunchKernelGGL(k_bias, dim3(16),  dim3(256), 0, stream, bt, biasT);
    hipLaunchKernelGGL(k_xcvt, dim3(4096), dim3(256), 0, stream, x, xt);
    hipLaunchKernelGGL(k_qkv,  dim3(6144), dim3(256), 0, stream,
                       xt, qkvwb, qkvb, gq, gk, wv_b);
    hipLaunchKernelGGL(k_attn3, dim3(4096), dim3(256), 0, stream,
                       gq, gk, wv_b, lsc, biasT, wout_b);
    hipLaunchKernelGGL(k_proj, dim3(2048), dim3(256), 0, stream,
                       wout_b, wv_b, pew, peb, pjwb, pjb, (float*)d_out);
}

// Round 18
// 353.102 us; speedup vs baseline: 1.9365x; 1.0284x over previous
//
#include <hip/hip_runtime.h>

typedef unsigned short u16;
typedef unsigned int u32;
typedef short bf16x8 __attribute__((ext_vector_type(8)));
typedef float f32x4 __attribute__((ext_vector_type(4)));
typedef unsigned short u16x8 __attribute__((ext_vector_type(8)));
typedef unsigned short u16x4 __attribute__((ext_vector_type(4)));

#define DEVFN static __device__ __forceinline__

DEVFN u16 f2b(float f) {
    u32 u = __builtin_bit_cast(u32, f);
    u += 0x7FFFu + ((u >> 16) & 1u);
    return (u16)(u >> 16);
}
DEVFN float b2f(u16 h) {
    u32 u = ((u32)h) << 16;
    return __builtin_bit_cast(float, u);
}

typedef const __attribute__((address_space(1))) unsigned int glb_u32;
typedef __attribute__((address_space(3))) unsigned int lds_u32;
DEVFN void gload_lds16(const u16* g, u16* l) {
    __builtin_amdgcn_global_load_lds((glb_u32*)g, (lds_u32*)l, 16, 0, 0);
}

// ----------------------------------------------------------------- pre ----
// Fused pre-pass: blocks [0,4096) = xcvt, [4096,4864) = weight convert,
// [4864,5089) = CPB MLP -> 16*sigmoid -> biasT scatter (bias kernel fused:
// block p writes exactly the (k,q) positions with idx(k,q)==p).
__global__ __launch_bounds__(256) void k_pre(
    const float* __restrict__ x, u16* __restrict__ xt,
    const float* __restrict__ qkvw, const float* __restrict__ pjw,
    u16* __restrict__ qkvwb, u16* __restrict__ pjwb,
    const float* __restrict__ w1, const float* __restrict__ b1,
    const float* __restrict__ w2, float* __restrict__ biasT) {
    __shared__ float red[4][8];
    const int bid = blockIdx.x;
    const int tid = threadIdx.x;

    if (bid < 4096) {
        // ---- xcvt (R17 verbatim): x fp32 NCHW -> swizzled bf16 tiles ----
        const int xcd = bid & 7;
        const int i = bid >> 3;                  // 0..511
        const int rowblk = xcd * 128 + (i >> 2);
        const int c = i & 3;
        const int g = tid & 7;
        const int tseg = tid >> 3;
        const int tok0 = tseg * 4;
        const float* src = x + ((size_t)(rowblk >> 7) * 256 + c * 64 + g * 8) * 16384
                             + (rowblk & 127) * 128 + tok0;
        float4 v[8];
        #pragma unroll
        for (int j = 0; j < 8; ++j)
            v[j] = *(const float4*)(src + (size_t)j * 16384);
        u16x8 o0, o1, o2, o3;
        #pragma unroll
        for (int j = 0; j < 8; ++j) {
            o0[j] = f2b(v[j].x);
            o1[j] = f2b(v[j].y);
            o2[j] = f2b(v[j].z);
            o3[j] = f2b(v[j].w);
        }
        const int s0 = g ^ ((tseg ^ (tok0 + 0)) & 7);
        const int s1 = g ^ ((tseg ^ (tok0 + 1)) & 7);
        const int s2 = g ^ ((tseg ^ (tok0 + 2)) & 7);
        const int s3 = g ^ ((tseg ^ (tok0 + 3)) & 7);
        u16* dst = xt + ((size_t)rowblk * 4 + c) * 8192;
        *(u16x8*)&dst[(tok0 + 0) * 64 + (s0 << 3)] = o0;
        *(u16x8*)&dst[(tok0 + 1) * 64 + (s1 << 3)] = o1;
        *(u16x8*)&dst[(tok0 + 2) * 64 + (s2 << 3)] = o2;
        *(u16x8*)&dst[(tok0 + 3) * 64 + (s3 << 3)] = o3;
    } else if (bid < 4864) {
        // ---- weight convert (R17 k_prep verbatim) ----
        const int id = (bid - 4096) * 256 + tid;
        if (id < 196608) qkvwb[id] = f2b(qkvw[id]);
        if (id < 65536)  pjwb[id]  = f2b(pjw[id]);
    } else {
        // ---- CPB MLP + fused bias scatter ----
        const int p = bid - 4864;       // 0..224
        const int d = tid;              // hidden dim 0..255
        const int d0 = p / 15, d1 = p % 15;
        const float v0 = (float)(d0 - 7) * (8.0f / 7.0f);
        const float v1 = (float)(d1 - 7) * (8.0f / 7.0f);
        const float t0 = copysignf(log2f(fabsf(v0) + 1.0f) * (1.0f / 3.0f), v0);
        const float t1 = copysignf(log2f(fabsf(v1) + 1.0f) * (1.0f / 3.0f), v1);
        const float h = fmaxf(t0 * w1[2 * d] + t1 * w1[2 * d + 1] + b1[d], 0.0f);
        float s[8];
        #pragma unroll
        for (int hh = 0; hh < 8; ++hh) s[hh] = h * w2[hh * 256 + d];
        #pragma unroll
        for (int m = 1; m < 64; m <<= 1)
            #pragma unroll
            for (int hh = 0; hh < 8; ++hh) s[hh] += __shfl_xor(s[hh], m, 64);
        const int wave = d >> 6, l = d & 63;
        if (l == 0)
            #pragma unroll
            for (int hh = 0; hh < 8; ++hh) red[wave][hh] = s[hh];
        __syncthreads();
        // scatter: (k,q) pairs with (q_hi-k_hi)==a, (q_lo-k_lo)==bb
        const int a  = d0 - 7, bb = d1 - 7;
        const int na = 8 - (a  < 0 ? -a  : a);
        const int nb = 8 - (bb < 0 ? -bb : bb);
        if (tid < na * nb) {
            const int i2 = tid / nb, j2 = tid % nb;
            const int k_hi = (a  < 0 ? -a  : 0) + i2;
            const int q_hi = k_hi + a;
            const int k_lo = (bb < 0 ? -bb : 0) + j2;
            const int q_lo = k_lo + bb;
            const int kq = k_hi * 8 + k_lo, q = q_hi * 8 + q_lo;
            #pragma unroll
            for (int hh = 0; hh < 8; ++hh) {
                const float sum = red[0][hh] + red[1][hh] + red[2][hh] + red[3][hh];
                biasT[hh * 4096 + kq * 64 + q] = 16.0f / (1.0f + expf(-sum));
            }
        }
    }
}

// ---------------------------------------------------------------- qkv -----
// R17 verbatim: gload_lds staging + weight-register dbuf, (256,3).
__global__ __launch_bounds__(256, 3) void k_qkv(
    const u16* __restrict__ xt, const u16* __restrict__ qkvw,
    const float* __restrict__ qkvb,
    u16* __restrict__ gq, u16* __restrict__ gk, u16* __restrict__ wv_g) {
    __shared__ __align__(16) u16 Xs[2][8192];  // [128 tok][64 ch] swizzled

    const int bid = blockIdx.x;                 // 6144 = 8 xcd * 128 rowblk * 6 ny
    const int xcd = bid & 7;
    const int idx = bid >> 3;
    const int ny = idx % 6;
    const int rowblk = xcd * 128 + idx / 6;
    const int b = rowblk >> 7, row = rowblk & 127;
    const int which = ny >> 1, half = ny & 1;

    const int tid = threadIdx.x;
    const int wave = tid >> 6, l = tid & 63, col = l & 15, quad = l >> 4;
    const int th = wave >> 1;
    const int oq = wave & 1;
    const int obase = half * 128 + oq * 64;

    int orow[4];
    #pragma unroll
    for (int nt = 0; nt < 4; ++nt) {
        const int oo = obase + nt * 16 + col;
        orow[nt] = (oo >> 5) * 96 + which * 32 + (oo & 31);
    }

    f32x4 acc[4][4];                            // [nt(och)][mt(tok)]
    #pragma unroll
    for (int i = 0; i < 4; ++i)
        #pragma unroll
        for (int j = 0; j < 4; ++j) acc[i][j] = f32x4{0.f, 0.f, 0.f, 0.f};

    const u16* xtb = xt + (size_t)rowblk * 32768;

    auto stage = [&](int c, int buf) {
        const u16* src = xtb + c * 8192 + wave * 2048 + l * 8;
        u16* dst = &Xs[buf][wave * 2048];
        #pragma unroll
        for (int i = 0; i < 4; ++i)
            gload_lds16(src + i * 512, dst + i * 512);
    };
    auto loadW = [&](int c, bf16x8* bw) {
        #pragma unroll
        for (int kk = 0; kk < 2; ++kk)
            #pragma unroll
            for (int nt = 0; nt < 4; ++nt)
                bw[kk * 4 + nt] = *(const bf16x8*)&qkvw[(size_t)orow[nt] * 256 +
                                                        c * 64 + kk * 32 + quad * 8];
    };
    auto gemm = [&](int buf, const bf16x8* bw) {
        #pragma unroll
        for (int kk = 0; kk < 2; ++kk) {
            const int lchunk = kk * 4 + quad;
            bf16x8 af[4];
            #pragma unroll
            for (int mt = 0; mt < 4; ++mt) {
                const int tok = th * 64 + mt * 16 + col;
                const int slot = lchunk ^ (((tok >> 2) ^ tok) & 7);
                af[mt] = *(const bf16x8*)&Xs[buf][tok * 64 + (slot << 3)];
            }
            #pragma unroll
            for (int nt = 0; nt < 4; ++nt)
                #pragma unroll
                for (int mt = 0; mt < 4; ++mt)
                    acc[nt][mt] = __builtin_amdgcn_mfma_f32_16x16x32_bf16(
                        bw[kk * 4 + nt], af[mt], acc[nt][mt], 0, 0, 0);
        }
    };

    bf16x8 bwA[8], bwB[8];
    stage(0, 0);
    loadW(0, bwA);
    __syncthreads();
    #pragma unroll
    for (int c = 0; c < 4; ++c) {
        if (c < 3) {
            stage(c + 1, (c + 1) & 1);          // async prefetch (T14)
            loadW(c + 1, (c & 1) ? bwA : bwB);  // weight prefetch
        }
        gemm(c & 1, (c & 1) ? bwB : bwA);
        __syncthreads();
    }

    // epilogue: D[och][tok]
    const int hA = obase >> 5;
    f32x4 bqv[4];
    #pragma unroll
    for (int nt = 0; nt < 4; ++nt) {
        const int oo = obase + nt * 16 + quad * 4;
        bqv[nt] = *(const f32x4*)&qkvb[(oo >> 5) * 96 + which * 32 + (oo & 31)];
    }
    #pragma unroll
    for (int mt = 0; mt < 4; ++mt) {
        const int tok = th * 64 + mt * 16 + col;
        const int win = b * 256 + (row >> 3) * 16 + (tok >> 3);
        const int tk = (row & 7) * 8 + (tok & 7);
        float v[4][4];
        #pragma unroll
        for (int nt = 0; nt < 4; ++nt)
            #pragma unroll
            for (int r = 0; r < 4; ++r)
                v[nt][r] = acc[nt][mt][r] + bqv[nt][r];
        if (which < 2) {
            float sA = 0.f, sB = 0.f;
            #pragma unroll
            for (int r = 0; r < 4; ++r) {
                sA += v[0][r] * v[0][r] + v[1][r] * v[1][r];
                sB += v[2][r] * v[2][r] + v[3][r] * v[3][r];
            }
            sA += __shfl_xor(sA, 16, 64);
            sA += __shfl_xor(sA, 32, 64);
            sB += __shfl_xor(sB, 16, 64);
            sB += __shfl_xor(sB, 32, 64);
            const float iA = 1.0f / fmaxf(sqrtf(sA), 1e-12f);
            const float iB = 1.0f / fmaxf(sqrtf(sB), 1e-12f);
            #pragma unroll
            for (int r = 0; r < 4; ++r) {
                v[0][r] *= iA; v[1][r] *= iA;
                v[2][r] *= iB; v[3][r] *= iB;
            }
        }
        #pragma unroll
        for (int nt = 0; nt < 4; ++nt) {
            u16x4 ov;
            #pragma unroll
            for (int r = 0; r < 4; ++r) ov[r] = f2b(v[nt][r]);
            if (which == 2) {
                *(u16x4*)&wv_g[((size_t)win * 64 + tk) * 256 + obase + nt * 16 + quad * 4] = ov;
            } else {
                u16* G = (which == 0) ? gq : gk;
                const int h = hA + (nt >> 1);
                const int d = (nt & 1) * 16 + quad * 4;
                *(u16x4*)&G[((size_t)(win * 8 + h) * 64 + tk) * 32 + d] = ov;
            }
        }
    }
}

// ---------------------------------------------------------------- attn ----
// R17 verbatim: S^T layout, in-register softmax, P^T from regs, XCD-aligned.
__global__ __launch_bounds__(256, 3) void k_attn3(
    const u16* __restrict__ gq, const u16* __restrict__ gk,
    const u16* __restrict__ wv_g,
    const float* __restrict__ lsc, const float* __restrict__ biasT,
    u16* __restrict__ wout_g) {
    __shared__ __align__(16) u16 scr[4][2048];  // per wave: v_t only

    const int tid = threadIdx.x;
    const int wave = tid >> 6, l = tid & 63, col = l & 15, quad = l >> 4;
    const int bid = blockIdx.x;                 // 4096 = 8 xcd * 512
    const int xcd = bid & 7;
    const int jl = (bid >> 3) * 4 + wave;       // 0..2047 per xcd
    const int h = jl >> 8;
    const int win = xcd * 256 + (jl & 255);
    u16* const v_t = scr[wave];  // [32 d][64 pi-slot] swz(d&7)

    u16x8 sv[4];
    #pragma unroll
    for (int it = 0; it < 4; ++it) {
        const int idx = it * 64 + l;
        const int tok = idx & 63, dblk = idx >> 6;
        sv[it] = *(const u16x8*)&wv_g[((size_t)win * 64 + tok) * 256 + h * 32 + dblk * 8];
    }
    const u16* const qbp = gq + (size_t)(win * 8 + h) * 2048;
    const u16* const kbp = gk + (size_t)(win * 8 + h) * 2048;
    bf16x8 ak[4], bq[4];
    #pragma unroll
    for (int mt = 0; mt < 4; ++mt)
        ak[mt] = *(const bf16x8*)&kbp[(mt * 16 + col) * 32 + quad * 8];
    #pragma unroll
    for (int nt = 0; nt < 4; ++nt)
        bq[nt] = *(const bf16x8*)&qbp[(nt * 16 + col) * 32 + quad * 8];

    #pragma unroll
    for (int it = 0; it < 4; ++it) {
        const int idx = it * 64 + l;
        const int tok = idx & 63, dblk = idx >> 6;
        const int g = (tok >> 5) * 4 + ((tok >> 2) & 3);
        const int jj = ((tok >> 4) & 1) * 4 + (tok & 3);
        #pragma unroll
        for (int j = 0; j < 8; ++j) {
            const int d = dblk * 8 + j;
            v_t[d * 64 + (((g ^ (d & 7)) << 3) | jj)] = sv[it][j];
        }
    }

    const f32x4 zero4 = {0.f, 0.f, 0.f, 0.f};
    f32x4 sacc[4][4];
    #pragma unroll
    for (int mt = 0; mt < 4; ++mt)
        #pragma unroll
        for (int nt = 0; nt < 4; ++nt)
            sacc[mt][nt] = __builtin_amdgcn_mfma_f32_16x16x32_bf16(ak[mt], bq[nt], zero4, 0, 0, 0);

    const float ls = expf(fminf(lsc[h], 4.6051701859880914f));
    const float* bT = biasT + h * 4096;
    #pragma unroll
    for (int nt = 0; nt < 4; ++nt) {
        const int q = nt * 16 + col;
        float v[4][4];
        float mx = -1e30f;
        #pragma unroll
        for (int mt = 0; mt < 4; ++mt)
            #pragma unroll
            for (int r = 0; r < 4; ++r) {
                v[mt][r] = sacc[mt][nt][r] * ls + bT[(mt * 16 + quad * 4 + r) * 64 + q];
                mx = fmaxf(mx, v[mt][r]);
            }
        mx = fmaxf(mx, __shfl_xor(mx, 16, 64));
        mx = fmaxf(mx, __shfl_xor(mx, 32, 64));
        float s = 0.f;
        #pragma unroll
        for (int mt = 0; mt < 4; ++mt)
            #pragma unroll
            for (int r = 0; r < 4; ++r) {
                v[mt][r] = expf(v[mt][r] - mx);
                s += v[mt][r];
            }
        s += __shfl_xor(s, 16, 64);
        s += __shfl_xor(s, 32, 64);
        const float inv = 1.0f / s;
        #pragma unroll
        for (int mt = 0; mt < 4; ++mt)
            #pragma unroll
            for (int r = 0; r < 4; ++r)
                sacc[mt][nt][r] = v[mt][r] * inv;
    }

    f32x4 oacc[2][4];
    #pragma unroll
    for (int i = 0; i < 2; ++i)
        #pragma unroll
        for (int j = 0; j < 4; ++j) oacc[i][j] = zero4;
    #pragma unroll
    for (int kk = 0; kk < 2; ++kk) {
        bf16x8 av[2];
        #pragma unroll
        for (int dt = 0; dt < 2; ++dt) {
            const int d = dt * 16 + col;
            av[dt] = *(const bf16x8*)&v_t[d * 64 + (((kk * 4 + quad) ^ (d & 7)) << 3)];
        }
        #pragma unroll
        for (int nt = 0; nt < 4; ++nt) {
            union { u16x8 u; bf16x8 b; } pk;
            #pragma unroll
            for (int j = 0; j < 4; ++j) {
                pk.u[j]     = f2b(sacc[kk * 2][nt][j]);
                pk.u[j + 4] = f2b(sacc[kk * 2 + 1][nt][j]);
            }
            #pragma unroll
            for (int dt = 0; dt < 2; ++dt)
                oacc[dt][nt] = __builtin_amdgcn_mfma_f32_16x16x32_bf16(
                    av[dt], pk.b, oacc[dt][nt], 0, 0, 0);
        }
    }
    #pragma unroll
    for (int dt = 0; dt < 2; ++dt)
        #pragma unroll
        for (int qt = 0; qt < 4; ++qt) {
            const int t = qt * 16 + col;
            u16x4 ov;
            #pragma unroll
            for (int r = 0; r < 4; ++r) ov[r] = f2b(oacc[dt][qt][r]);
            *(u16x4*)&wout_g[((size_t)win * 64 + t) * 256 + h * 32 + dt * 16 + quad * 4] = ov;
        }
}

// ---------------------------------------------------------------- proj ----
// R17 verbatim: operand-swapped GEMM, float4 stores, XCD-aligned win map.
__global__ __launch_bounds__(256, 4) void k_proj(
    const u16* __restrict__ wout_g, const u16* __restrict__ wv_g,
    const float* __restrict__ pe_w, const float* __restrict__ pe_b,
    const u16* __restrict__ pjw, const float* __restrict__ pjb,
    float* __restrict__ out) {
    __shared__ __align__(16) u16 y_s[64 * 256];
    const int bid0 = blockIdx.x;                // 2048 = 8 xcd * 256
    const int win = (bid0 & 7) * 256 + (bid0 >> 3);
    const int b = win >> 8;
    const int h0 = ((win >> 4) & 15) * 8;
    const int w0 = (win & 15) * 8;
    const int tid = threadIdx.x;
    const int cg = tid & 31, ch = cg * 8;
    const int psub = tid >> 5;

    float pw[9][8];
    #pragma unroll
    for (int j = 0; j < 8; ++j)
        #pragma unroll
        for (int k = 0; k < 9; ++k) pw[k][j] = pe_w[(ch + j) * 9 + k];
    float pb[8];
    #pragma unroll
    for (int j = 0; j < 8; ++j) pb[j] = pe_b[ch + j];

    for (int it = 0; it < 8; ++it) {
        const int p = it * 8 + psub;
        const int gh = h0 + (p >> 3), gw = w0 + (p & 7);
        float a[8];
        {
            const bf16x8 ov = *(const bf16x8*)&wout_g[((size_t)win * 64 + p) * 256 + ch];
            #pragma unroll
            for (int j = 0; j < 8; ++j) a[j] = b2f((u16)ov[j]) + pb[j];
        }
        #pragma unroll
        for (int dy = -1; dy <= 1; ++dy)
            #pragma unroll
            for (int dx = -1; dx <= 1; ++dx) {
                const int hh = gh + dy, ww2 = gw + dx;
                if (hh < 0 || hh >= 128 || ww2 < 0 || ww2 >= 128) continue;
                const int nwin = b * 256 + (hh >> 3) * 16 + (ww2 >> 3);
                const int ntk = (hh & 7) * 8 + (ww2 & 7);
                const bf16x8 vv = *(const bf16x8*)&wv_g[((size_t)nwin * 64 + ntk) * 256 + ch];
                const int k = (dy + 1) * 3 + (dx + 1);
                #pragma unroll
                for (int j = 0; j < 8; ++j) a[j] += b2f((u16)vv[j]) * pw[k][j];
            }
        u16x8 tmp;
        #pragma unroll
        for (int j = 0; j < 8; ++j) tmp[j] = f2b(a[j]);
        *(u16x8*)&y_s[p * 256 + (((ch >> 3) ^ (p & 7)) << 3)] = tmp;
    }
    __syncthreads();

    const int wave = tid >> 6, l = tid & 63;
    const int col = l & 15, quad = l >> 4;
    const f32x4 zero4 = {0.f, 0.f, 0.f, 0.f};
    f32x4 macc[4][4];                    // [pt(tok)][ot(och)]
    #pragma unroll
    for (int pt = 0; pt < 4; ++pt)
        #pragma unroll
        for (int ot = 0; ot < 4; ++ot) macc[pt][ot] = zero4;
    const int ob = wave * 64;
    for (int kk = 0; kk < 8; ++kk) {
        const int cb = kk * 32 + quad * 8;
        bf16x8 aw[4], by[4];
        #pragma unroll
        for (int ot = 0; ot < 4; ++ot)
            aw[ot] = *(const bf16x8*)&pjw[(size_t)(ob + ot * 16 + col) * 256 + cb];
        #pragma unroll
        for (int pt = 0; pt < 4; ++pt) {
            const int p = pt * 16 + col;
            by[pt] = *(const bf16x8*)&y_s[p * 256 + (((cb >> 3) ^ (p & 7)) << 3)];
        }
        #pragma unroll
        for (int pt = 0; pt < 4; ++pt)
            #pragma unroll
            for (int ot = 0; ot < 4; ++ot)
                macc[pt][ot] = __builtin_amdgcn_mfma_f32_16x16x32_bf16(
                    by[pt], aw[ot], macc[pt][ot], 0, 0, 0);
    }
    #pragma unroll
    for (int ot = 0; ot < 4; ++ot) {
        const int o = ob + ot * 16 + col;
        const float pbv = pjb[o];
        #pragma unroll
        for (int pt = 0; pt < 4; ++pt) {
            const int p0 = pt * 16 + quad * 4;
            float4 ov;
            ov.x = macc[pt][ot][0] + pbv;
            ov.y = macc[pt][ot][1] + pbv;
            ov.z = macc[pt][ot][2] + pbv;
            ov.w = macc[pt][ot][3] + pbv;
            *(float4*)&out[((size_t)(b * 256 + o)) * 16384 +
                           (h0 + (p0 >> 3)) * 128 + w0 + (p0 & 7)] = ov;
        }
    }
}

// -------------------------------------------------------------- launch ----
extern "C" void kernel_launch(void* const* d_in, const int* in_sizes, int n_in,
                              void* d_out, int out_size, void* d_ws, size_t ws_size,
                              hipStream_t stream) {
    const float* x    = (const float*)d_in[0];
    const float* qkvw = (const float*)d_in[1];
    const float* qkvb = (const float*)d_in[2];
    const float* pjw  = (const float*)d_in[3];
    const float* pjb  = (const float*)d_in[4];
    const float* pew  = (const float*)d_in[5];
    const float* peb  = (const float*)d_in[6];
    const float* lsc  = (const float*)d_in[7];
    const float* w1   = (const float*)d_in[8];
    const float* b1   = (const float*)d_in[9];
    const float* w2   = (const float*)d_in[10];

    char* ws = (char*)d_ws;
    u16* wv_b    = (u16*)(ws);                                    // 64 MiB
    u16* wout_b  = (u16*)(ws + (64ull << 20));                    // 64 MiB
    u16* qkvwb   = (u16*)(ws + (128ull << 20));                   // 384 KiB
    u16* pjwb    = (u16*)(ws + (128ull << 20) + 393216);          // 128 KiB
    float* biasT = (float*)(ws + (128ull << 20) + 393216 + 131072); // 128 KiB

    // xt (swizzled bf16 x) lives in wout_b: dead until k_attn3 writes wout,
    // and k_qkv (its only reader) completes before k_attn3 starts.
    u16* xt = wout_b;
    // q/k scratch lives inside d_out; dead before k_proj overwrites d_out.
    u16* gq = (u16*)d_out;
    u16* gk = gq + 33554432u;

    hipLaunchKernelGGL(k_pre, dim3(5089), dim3(256), 0, stream,
                       x, xt, qkvw, pjw, qkvwb, pjwb, w1, b1, w2, biasT);
    hipLaunchKernelGGL(k_qkv, dim3(6144), dim3(256), 0, stream,
                       xt, qkvwb, qkvb, gq, gk, wv_b);
    hipLaunchKernelGGL(k_attn3, dim3(4096), dim3(256), 0, stream,
                       gq, gk, wv_b, lsc, biasT, wout_b);
    hipLaunchKernelGGL(k_proj, dim3(2048), dim3(256), 0, stream,
                       wout_b, wv_b, pew, peb, pjwb, pjb, (float*)d_out);
}

// Round 19
// 349.572 us; speedup vs baseline: 1.9561x; 1.0101x over previous
//
#include <hip/hip_runtime.h>

typedef unsigned short u16;
typedef unsigned int u32;
typedef short bf16x8 __attribute__((ext_vector_type(8)));
typedef float f32x4 __attribute__((ext_vector_type(4)));
typedef unsigned short u16x8 __attribute__((ext_vector_type(8)));
typedef unsigned short u16x4 __attribute__((ext_vector_type(4)));

#define DEVFN static __device__ __forceinline__

DEVFN u16 f2b(float f) {
    u32 u = __builtin_bit_cast(u32, f);
    u += 0x7FFFu + ((u >> 16) & 1u);
    return (u16)(u >> 16);
}
DEVFN float b2f(u16 h) {
    u32 u = ((u32)h) << 16;
    return __builtin_bit_cast(float, u);
}

typedef const __attribute__((address_space(1))) unsigned int glb_u32;
typedef __attribute__((address_space(3))) unsigned int lds_u32;
DEVFN void gload_lds16(const u16* g, u16* l) {
    __builtin_amdgcn_global_load_lds((glb_u32*)g, (lds_u32*)l, 16, 0, 0);
}

// ----------------------------------------------------------------- pre ----
// Fused pre-pass (R18 verbatim): xcvt | weight convert | CPB->biasT scatter.
__global__ __launch_bounds__(256) void k_pre(
    const float* __restrict__ x, u16* __restrict__ xt,
    const float* __restrict__ qkvw, const float* __restrict__ pjw,
    u16* __restrict__ qkvwb, u16* __restrict__ pjwb,
    const float* __restrict__ w1, const float* __restrict__ b1,
    const float* __restrict__ w2, float* __restrict__ biasT) {
    __shared__ float red[4][8];
    const int bid = blockIdx.x;
    const int tid = threadIdx.x;

    if (bid < 4096) {
        const int xcd = bid & 7;
        const int i = bid >> 3;
        const int rowblk = xcd * 128 + (i >> 2);
        const int c = i & 3;
        const int g = tid & 7;
        const int tseg = tid >> 3;
        const int tok0 = tseg * 4;
        const float* src = x + ((size_t)(rowblk >> 7) * 256 + c * 64 + g * 8) * 16384
                             + (rowblk & 127) * 128 + tok0;
        float4 v[8];
        #pragma unroll
        for (int j = 0; j < 8; ++j)
            v[j] = *(const float4*)(src + (size_t)j * 16384);
        u16x8 o0, o1, o2, o3;
        #pragma unroll
        for (int j = 0; j < 8; ++j) {
            o0[j] = f2b(v[j].x);
            o1[j] = f2b(v[j].y);
            o2[j] = f2b(v[j].z);
            o3[j] = f2b(v[j].w);
        }
        const int s0 = g ^ ((tseg ^ (tok0 + 0)) & 7);
        const int s1 = g ^ ((tseg ^ (tok0 + 1)) & 7);
        const int s2 = g ^ ((tseg ^ (tok0 + 2)) & 7);
        const int s3 = g ^ ((tseg ^ (tok0 + 3)) & 7);
        u16* dst = xt + ((size_t)rowblk * 4 + c) * 8192;
        *(u16x8*)&dst[(tok0 + 0) * 64 + (s0 << 3)] = o0;
        *(u16x8*)&dst[(tok0 + 1) * 64 + (s1 << 3)] = o1;
        *(u16x8*)&dst[(tok0 + 2) * 64 + (s2 << 3)] = o2;
        *(u16x8*)&dst[(tok0 + 3) * 64 + (s3 << 3)] = o3;
    } else if (bid < 4864) {
        const int id = (bid - 4096) * 256 + tid;
        if (id < 196608) qkvwb[id] = f2b(qkvw[id]);
        if (id < 65536)  pjwb[id]  = f2b(pjw[id]);
    } else {
        const int p = bid - 4864;
        const int d = tid;
        const int d0 = p / 15, d1 = p % 15;
        const float v0 = (float)(d0 - 7) * (8.0f / 7.0f);
        const float v1 = (float)(d1 - 7) * (8.0f / 7.0f);
        const float t0 = copysignf(log2f(fabsf(v0) + 1.0f) * (1.0f / 3.0f), v0);
        const float t1 = copysignf(log2f(fabsf(v1) + 1.0f) * (1.0f / 3.0f), v1);
        const float h = fmaxf(t0 * w1[2 * d] + t1 * w1[2 * d + 1] + b1[d], 0.0f);
        float s[8];
        #pragma unroll
        for (int hh = 0; hh < 8; ++hh) s[hh] = h * w2[hh * 256 + d];
        #pragma unroll
        for (int m = 1; m < 64; m <<= 1)
            #pragma unroll
            for (int hh = 0; hh < 8; ++hh) s[hh] += __shfl_xor(s[hh], m, 64);
        const int wave = d >> 6, l = d & 63;
        if (l == 0)
            #pragma unroll
            for (int hh = 0; hh < 8; ++hh) red[wave][hh] = s[hh];
        __syncthreads();
        const int a  = d0 - 7, bb = d1 - 7;
        const int na = 8 - (a  < 0 ? -a  : a);
        const int nb = 8 - (bb < 0 ? -bb : bb);
        if (tid < na * nb) {
            const int i2 = tid / nb, j2 = tid % nb;
            const int k_hi = (a  < 0 ? -a  : 0) + i2;
            const int q_hi = k_hi + a;
            const int k_lo = (bb < 0 ? -bb : 0) + j2;
            const int q_lo = k_lo + bb;
            const int kq = k_hi * 8 + k_lo, q = q_hi * 8 + q_lo;
            #pragma unroll
            for (int hh = 0; hh < 8; ++hh) {
                const float sum = red[0][hh] + red[1][hh] + red[2][hh] + red[3][hh];
                biasT[hh * 4096 + kq * 64 + q] = 16.0f / (1.0f + expf(-sum));
            }
        }
    }
}

// ---------------------------------------------------------------- qkv -----
// T4-lite: raw s_barrier + counted vmcnt (loads stay in flight across
// barriers), 3-buffer LDS with stage prefetch distance 2. Counts derived
// conservatively from program order (see journal): 12,12,12,8.
__global__ __launch_bounds__(256, 3) void k_qkv(
    const u16* __restrict__ xt, const u16* __restrict__ qkvw,
    const float* __restrict__ qkvb,
    u16* __restrict__ gq, u16* __restrict__ gk, u16* __restrict__ wv_g) {
    __shared__ __align__(16) u16 Xs[3][8192];  // 3 bufs x [128 tok][64 ch]

    const int bid = blockIdx.x;                 // 6144 = 8 xcd * 128 rowblk * 6 ny
    const int xcd = bid & 7;
    const int idx = bid >> 3;
    const int ny = idx % 6;
    const int rowblk = xcd * 128 + idx / 6;
    const int b = rowblk >> 7, row = rowblk & 127;
    const int which = ny >> 1, half = ny & 1;

    const int tid = threadIdx.x;
    const int wave = tid >> 6, l = tid & 63, col = l & 15, quad = l >> 4;
    const int th = wave >> 1;
    const int oq = wave & 1;
    const int obase = half * 128 + oq * 64;

    int orow[4];
    #pragma unroll
    for (int nt = 0; nt < 4; ++nt) {
        const int oo = obase + nt * 16 + col;
        orow[nt] = (oo >> 5) * 96 + which * 32 + (oo & 31);
    }

    f32x4 acc[4][4];                            // [nt(och)][mt(tok)]
    #pragma unroll
    for (int i = 0; i < 4; ++i)
        #pragma unroll
        for (int j = 0; j < 4; ++j) acc[i][j] = f32x4{0.f, 0.f, 0.f, 0.f};

    const u16* xtb = xt + (size_t)rowblk * 32768;

    auto stage = [&](int c, int buf) {
        const u16* src = xtb + c * 8192 + wave * 2048 + l * 8;
        u16* dst = &Xs[buf][wave * 2048];
        #pragma unroll
        for (int i = 0; i < 4; ++i)
            gload_lds16(src + i * 512, dst + i * 512);
    };
    auto loadW = [&](int c, bf16x8* bw) {
        #pragma unroll
        for (int kk = 0; kk < 2; ++kk)
            #pragma unroll
            for (int nt = 0; nt < 4; ++nt)
                bw[kk * 4 + nt] = *(const bf16x8*)&qkvw[(size_t)orow[nt] * 256 +
                                                        c * 64 + kk * 32 + quad * 8];
    };
    auto gemm = [&](int buf, const bf16x8* bw) {
        #pragma unroll
        for (int kk = 0; kk < 2; ++kk) {
            const int lchunk = kk * 4 + quad;
            bf16x8 af[4];
            #pragma unroll
            for (int mt = 0; mt < 4; ++mt) {
                const int tok = th * 64 + mt * 16 + col;
                const int slot = lchunk ^ (((tok >> 2) ^ tok) & 7);
                af[mt] = *(const bf16x8*)&Xs[buf][tok * 64 + (slot << 3)];
            }
            #pragma unroll
            for (int nt = 0; nt < 4; ++nt)
                #pragma unroll
                for (int mt = 0; mt < 4; ++mt)
                    acc[nt][mt] = __builtin_amdgcn_mfma_f32_16x16x32_bf16(
                        bw[kk * 4 + nt], af[mt], acc[nt][mt], 0, 0, 0);
        }
    };

    bf16x8 bwA[8], bwB[8];
    // prologue: s0, s1, lw0.  Need s0 before barrier: newer = s1(4)+lw0(8)=12.
    stage(0, 0);
    stage(1, 1);
    loadW(0, bwA);
    asm volatile("s_waitcnt vmcnt(12)" ::: "memory");
    __builtin_amdgcn_s_barrier();
    #pragma unroll
    for (int c = 0; c < 4; ++c) {
        if (c < 2) stage(c + 2, (c + 2) % 3);        // prefetch distance 2
        if (c < 3) loadW(c + 1, (c & 1) ? bwA : bwB);
        gemm(c % 3, (c & 1) ? bwB : bwA);
        if (c < 3) {
            // end iter c needs stage(c+1) complete for next gemm.
            // newer-than-s(c+1): c=0: lw0+s2+lw1 keep 12 (s2+lw1);
            // c=1: lw1+s3+lw2 keep 12 (s3+lw2); c=2: lw2+lw3 keep 8 (lw3).
            if (c == 2) asm volatile("s_waitcnt vmcnt(8)" ::: "memory");
            else        asm volatile("s_waitcnt vmcnt(12)" ::: "memory");
            __builtin_amdgcn_s_barrier();
        }
    }

    // epilogue: D[och][tok]  (R18 verbatim)
    const int hA = obase >> 5;
    f32x4 bqv[4];
    #pragma unroll
    for (int nt = 0; nt < 4; ++nt) {
        const int oo = obase + nt * 16 + quad * 4;
        bqv[nt] = *(const f32x4*)&qkvb[(oo >> 5) * 96 + which * 32 + (oo & 31)];
    }
    #pragma unroll
    for (int mt = 0; mt < 4; ++mt) {
        const int tok = th * 64 + mt * 16 + col;
        const int win = b * 256 + (row >> 3) * 16 + (tok >> 3);
        const int tk = (row & 7) * 8 + (tok & 7);
        float v[4][4];
        #pragma unroll
        for (int nt = 0; nt < 4; ++nt)
            #pragma unroll
            for (int r = 0; r < 4; ++r)
                v[nt][r] = acc[nt][mt][r] + bqv[nt][r];
        if (which < 2) {
            float sA = 0.f, sB = 0.f;
            #pragma unroll
            for (int r = 0; r < 4; ++r) {
                sA += v[0][r] * v[0][r] + v[1][r] * v[1][r];
                sB += v[2][r] * v[2][r] + v[3][r] * v[3][r];
            }
            sA += __shfl_xor(sA, 16, 64);
            sA += __shfl_xor(sA, 32, 64);
            sB += __shfl_xor(sB, 16, 64);
            sB += __shfl_xor(sB, 32, 64);
            const float iA = 1.0f / fmaxf(sqrtf(sA), 1e-12f);
            const float iB = 1.0f / fmaxf(sqrtf(sB), 1e-12f);
            #pragma unroll
            for (int r = 0; r < 4; ++r) {
                v[0][r] *= iA; v[1][r] *= iA;
                v[2][r] *= iB; v[3][r] *= iB;
            }
        }
        #pragma unroll
        for (int nt = 0; nt < 4; ++nt) {
            u16x4 ov;
            #pragma unroll
            for (int r = 0; r < 4; ++r) ov[r] = f2b(v[nt][r]);
            if (which == 2) {
                *(u16x4*)&wv_g[((size_t)win * 64 + tk) * 256 + obase + nt * 16 + quad * 4] = ov;
            } else {
                u16* G = (which == 0) ? gq : gk;
                const int h = hA + (nt >> 1);
                const int d = (nt & 1) * 16 + quad * 4;
                *(u16x4*)&G[((size_t)(win * 8 + h) * 64 + tk) * 32 + d] = ov;
            }
        }
    }
}

// ---------------------------------------------------------------- attn ----
// R18 verbatim: S^T layout, in-register softmax, P^T from regs, XCD-aligned.
__global__ __launch_bounds__(256, 3) void k_attn3(
    const u16* __restrict__ gq, const u16* __restrict__ gk,
    const u16* __restrict__ wv_g,
    const float* __restrict__ lsc, const float* __restrict__ biasT,
    u16* __restrict__ wout_g) {
    __shared__ __align__(16) u16 scr[4][2048];  // per wave: v_t only

    const int tid = threadIdx.x;
    const int wave = tid >> 6, l = tid & 63, col = l & 15, quad = l >> 4;
    const int bid = blockIdx.x;                 // 4096 = 8 xcd * 512
    const int xcd = bid & 7;
    const int jl = (bid >> 3) * 4 + wave;       // 0..2047 per xcd
    const int h = jl >> 8;
    const int win = xcd * 256 + (jl & 255);
    u16* const v_t = scr[wave];  // [32 d][64 pi-slot] swz(d&7)

    u16x8 sv[4];
    #pragma unroll
    for (int it = 0; it < 4; ++it) {
        const int idx = it * 64 + l;
        const int tok = idx & 63, dblk = idx >> 6;
        sv[it] = *(const u16x8*)&wv_g[((size_t)win * 64 + tok) * 256 + h * 32 + dblk * 8];
    }
    const u16* const qbp = gq + (size_t)(win * 8 + h) * 2048;
    const u16* const kbp = gk + (size_t)(win * 8 + h) * 2048;
    bf16x8 ak[4], bq[4];
    #pragma unroll
    for (int mt = 0; mt < 4; ++mt)
        ak[mt] = *(const bf16x8*)&kbp[(mt * 16 + col) * 32 + quad * 8];
    #pragma unroll
    for (int nt = 0; nt < 4; ++nt)
        bq[nt] = *(const bf16x8*)&qbp[(nt * 16 + col) * 32 + quad * 8];

    #pragma unroll
    for (int it = 0; it < 4; ++it) {
        const int idx = it * 64 + l;
        const int tok = idx & 63, dblk = idx >> 6;
        const int g = (tok >> 5) * 4 + ((tok >> 2) & 3);
        const int jj = ((tok >> 4) & 1) * 4 + (tok & 3);
        #pragma unroll
        for (int j = 0; j < 8; ++j) {
            const int d = dblk * 8 + j;
            v_t[d * 64 + (((g ^ (d & 7)) << 3) | jj)] = sv[it][j];
        }
    }

    const f32x4 zero4 = {0.f, 0.f, 0.f, 0.f};
    f32x4 sacc[4][4];
    #pragma unroll
    for (int mt = 0; mt < 4; ++mt)
        #pragma unroll
        for (int nt = 0; nt < 4; ++nt)
            sacc[mt][nt] = __builtin_amdgcn_mfma_f32_16x16x32_bf16(ak[mt], bq[nt], zero4, 0, 0, 0);

    const float ls = expf(fminf(lsc[h], 4.6051701859880914f));
    const float* bT = biasT + h * 4096;
    #pragma unroll
    for (int nt = 0; nt < 4; ++nt) {
        const int q = nt * 16 + col;
        float v[4][4];
        float mx = -1e30f;
        #pragma unroll
        for (int mt = 0; mt < 4; ++mt)
            #pragma unroll
            for (int r = 0; r < 4; ++r) {
                v[mt][r] = sacc[mt][nt][r] * ls + bT[(mt * 16 + quad * 4 + r) * 64 + q];
                mx = fmaxf(mx, v[mt][r]);
            }
        mx = fmaxf(mx, __shfl_xor(mx, 16, 64));
        mx = fmaxf(mx, __shfl_xor(mx, 32, 64));
        float s = 0.f;
        #pragma unroll
        for (int mt = 0; mt < 4; ++mt)
            #pragma unroll
            for (int r = 0; r < 4; ++r) {
                v[mt][r] = expf(v[mt][r] - mx);
                s += v[mt][r];
            }
        s += __shfl_xor(s, 16, 64);
        s += __shfl_xor(s, 32, 64);
        const float inv = 1.0f / s;
        #pragma unroll
        for (int mt = 0; mt < 4; ++mt)
            #pragma unroll
            for (int r = 0; r < 4; ++r)
                sacc[mt][nt][r] = v[mt][r] * inv;
    }

    f32x4 oacc[2][4];
    #pragma unroll
    for (int i = 0; i < 2; ++i)
        #pragma unroll
        for (int j = 0; j < 4; ++j) oacc[i][j] = zero4;
    #pragma unroll
    for (int kk = 0; kk < 2; ++kk) {
        bf16x8 av[2];
        #pragma unroll
        for (int dt = 0; dt < 2; ++dt) {
            const int d = dt * 16 + col;
            av[dt] = *(const bf16x8*)&v_t[d * 64 + (((kk * 4 + quad) ^ (d & 7)) << 3)];
        }
        #pragma unroll
        for (int nt = 0; nt < 4; ++nt) {
            union { u16x8 u; bf16x8 b; } pk;
            #pragma unroll
            for (int j = 0; j < 4; ++j) {
                pk.u[j]     = f2b(sacc[kk * 2][nt][j]);
                pk.u[j + 4] = f2b(sacc[kk * 2 + 1][nt][j]);
            }
            #pragma unroll
            for (int dt = 0; dt < 2; ++dt)
                oacc[dt][nt] = __builtin_amdgcn_mfma_f32_16x16x32_bf16(
                    av[dt], pk.b, oacc[dt][nt], 0, 0, 0);
        }
    }
    #pragma unroll
    for (int dt = 0; dt < 2; ++dt)
        #pragma unroll
        for (int qt = 0; qt < 4; ++qt) {
            const int t = qt * 16 + col;
            u16x4 ov;
            #pragma unroll
            for (int r = 0; r < 4; ++r) ov[r] = f2b(oacc[dt][qt][r]);
            *(u16x4*)&wout_g[((size_t)win * 64 + t) * 256 + h * 32 + dt * 16 + quad * 4] = ov;
        }
}

// ---------------------------------------------------------------- proj ----
// R18 verbatim: operand-swapped GEMM, float4 stores, XCD-aligned win map.
__global__ __launch_bounds__(256, 4) void k_proj(
    const u16* __restrict__ wout_g, const u16* __restrict__ wv_g,
    const float* __restrict__ pe_w, const float* __restrict__ pe_b,
    const u16* __restrict__ pjw, const float* __restrict__ pjb,
    float* __restrict__ out) {
    __shared__ __align__(16) u16 y_s[64 * 256];
    const int bid0 = blockIdx.x;                // 2048 = 8 xcd * 256
    const int win = (bid0 & 7) * 256 + (bid0 >> 3);
    const int b = win >> 8;
    const int h0 = ((win >> 4) & 15) * 8;
    const int w0 = (win & 15) * 8;
    const int tid = threadIdx.x;
    const int cg = tid & 31, ch = cg * 8;
    const int psub = tid >> 5;

    float pw[9][8];
    #pragma unroll
    for (int j = 0; j < 8; ++j)
        #pragma unroll
        for (int k = 0; k < 9; ++k) pw[k][j] = pe_w[(ch + j) * 9 + k];
    float pb[8];
    #pragma unroll
    for (int j = 0; j < 8; ++j) pb[j] = pe_b[ch + j];

    for (int it = 0; it < 8; ++it) {
        const int p = it * 8 + psub;
        const int gh = h0 + (p >> 3), gw = w0 + (p & 7);
        float a[8];
        {
            const bf16x8 ov = *(const bf16x8*)&wout_g[((size_t)win * 64 + p) * 256 + ch];
            #pragma unroll
            for (int j = 0; j < 8; ++j) a[j] = b2f((u16)ov[j]) + pb[j];
        }
        #pragma unroll
        for (int dy = -1; dy <= 1; ++dy)
            #pragma unroll
            for (int dx = -1; dx <= 1; ++dx) {
                const int hh = gh + dy, ww2 = gw + dx;
                if (hh < 0 || hh >= 128 || ww2 < 0 || ww2 >= 128) continue;
                const int nwin = b * 256 + (hh >> 3) * 16 + (ww2 >> 3);
                const int ntk = (hh & 7) * 8 + (ww2 & 7);
                const bf16x8 vv = *(const bf16x8*)&wv_g[((size_t)nwin * 64 + ntk) * 256 + ch];
                const int k = (dy + 1) * 3 + (dx + 1);
                #pragma unroll
                for (int j = 0; j < 8; ++j) a[j] += b2f((u16)vv[j]) * pw[k][j];
            }
        u16x8 tmp;
        #pragma unroll
        for (int j = 0; j < 8; ++j) tmp[j] = f2b(a[j]);
        *(u16x8*)&y_s[p * 256 + (((ch >> 3) ^ (p & 7)) << 3)] = tmp;
    }
    __syncthreads();

    const int wave = tid >> 6, l = tid & 63;
    const int col = l & 15, quad = l >> 4;
    const f32x4 zero4 = {0.f, 0.f, 0.f, 0.f};
    f32x4 macc[4][4];                    // [pt(tok)][ot(och)]
    #pragma unroll
    for (int pt = 0; pt < 4; ++pt)
        #pragma unroll
        for (int ot = 0; ot < 4; ++ot) macc[pt][ot] = zero4;
    const int ob = wave * 64;
    for (int kk = 0; kk < 8; ++kk) {
        const int cb = kk * 32 + quad * 8;
        bf16x8 aw[4], by[4];
        #pragma unroll
        for (int ot = 0; ot < 4; ++ot)
            aw[ot] = *(const bf16x8*)&pjw[(size_t)(ob + ot * 16 + col) * 256 + cb];
        #pragma unroll
        for (int pt = 0; pt < 4; ++pt) {
            const int p = pt * 16 + col;
            by[pt] = *(const bf16x8*)&y_s[p * 256 + (((cb >> 3) ^ (p & 7)) << 3)];
        }
        #pragma unroll
        for (int pt = 0; pt < 4; ++pt)
            #pragma unroll
            for (int ot = 0; ot < 4; ++ot)
                macc[pt][ot] = __builtin_amdgcn_mfma_f32_16x16x32_bf16(
                    by[pt], aw[ot], macc[pt][ot], 0, 0, 0);
    }
    #pragma unroll
    for (int ot = 0; ot < 4; ++ot) {
        const int o = ob + ot * 16 + col;
        const float pbv = pjb[o];
        #pragma unroll
        for (int pt = 0; pt < 4; ++pt) {
            const int p0 = pt * 16 + quad * 4;
            float4 ov;
            ov.x = macc[pt][ot][0] + pbv;
            ov.y = macc[pt][ot][1] + pbv;
            ov.z = macc[pt][ot][2] + pbv;
            ov.w = macc[pt][ot][3] + pbv;
            *(float4*)&out[((size_t)(b * 256 + o)) * 16384 +
                           (h0 + (p0 >> 3)) * 128 + w0 + (p0 & 7)] = ov;
        }
    }
}

// -------------------------------------------------------------- launch ----
extern "C" void kernel_launch(void* const* d_in, const int* in_sizes, int n_in,
                              void* d_out, int out_size, void* d_ws, size_t ws_size,
                              hipStream_t stream) {
    const float* x    = (const float*)d_in[0];
    const float* qkvw = (const float*)d_in[1];
    const float* qkvb = (const float*)d_in[2];
    const float* pjw  = (const float*)d_in[3];
    const float* pjb  = (const float*)d_in[4];
    const float* pew  = (const float*)d_in[5];
    const float* peb  = (const float*)d_in[6];
    const float* lsc  = (const float*)d_in[7];
    const float* w1   = (const float*)d_in[8];
    const float* b1   = (const float*)d_in[9];
    const float* w2   = (const float*)d_in[10];

    char* ws = (char*)d_ws;
    u16* wv_b    = (u16*)(ws);                                    // 64 MiB
    u16* wout_b  = (u16*)(ws + (64ull << 20));                    // 64 MiB
    u16* qkvwb   = (u16*)(ws + (128ull << 20));                   // 384 KiB
    u16* pjwb    = (u16*)(ws + (128ull << 20) + 393216);          // 128 KiB
    float* biasT = (float*)(ws + (128ull << 20) + 393216 + 131072); // 128 KiB

    u16* xt = wout_b;
    u16* gq = (u16*)d_out;
    u16* gk = gq + 33554432u;

    hipLaunchKernelGGL(k_pre, dim3(5089), dim3(256), 0, stream,
                       x, xt, qkvw, pjw, qkvwb, pjwb, w1, b1, w2, biasT);
    hipLaunchKernelGGL(k_qkv, dim3(6144), dim3(256), 0, stream,
                       xt, qkvwb, qkvb, gq, gk, wv_b);
    hipLaunchKernelGGL(k_attn3, dim3(4096), dim3(256), 0, stream,
                       gq, gk, wv_b, lsc, biasT, wout_b);
    hipLaunchKernelGGL(k_proj, dim3(2048), dim3(256), 0, stream,
                       wout_b, wv_b, pew, peb, pjwb, pjb, (float*)d_out);
}

// Round 20
// 335.877 us; speedup vs baseline: 2.0358x; 1.0408x over previous
//
#include <hip/hip_runtime.h>

typedef unsigned short u16;
typedef unsigned int u32;
typedef short bf16x8 __attribute__((ext_vector_type(8)));
typedef float f32x4 __attribute__((ext_vector_type(4)));
typedef unsigned short u16x8 __attribute__((ext_vector_type(8)));
typedef unsigned short u16x4 __attribute__((ext_vector_type(4)));

#define DEVFN static __device__ __forceinline__

DEVFN u16 f2b(float f) {
    u32 u = __builtin_bit_cast(u32, f);
    u += 0x7FFFu + ((u >> 16) & 1u);
    return (u16)(u >> 16);
}
DEVFN float b2f(u16 h) {
    u32 u = ((u32)h) << 16;
    return __builtin_bit_cast(float, u);
}

typedef const __attribute__((address_space(1))) unsigned int glb_u32;
typedef __attribute__((address_space(3))) unsigned int lds_u32;
DEVFN void gload_lds16(const u16* g, u16* l) {
    __builtin_amdgcn_global_load_lds((glb_u32*)g, (lds_u32*)l, 16, 0, 0);
}

// ----------------------------------------------------------------- pre ----
// Fused pre-pass (R18 verbatim): xcvt | weight convert | CPB->biasT scatter.
__global__ __launch_bounds__(256) void k_pre(
    const float* __restrict__ x, u16* __restrict__ xt,
    const float* __restrict__ qkvw, const float* __restrict__ pjw,
    u16* __restrict__ qkvwb, u16* __restrict__ pjwb,
    const float* __restrict__ w1, const float* __restrict__ b1,
    const float* __restrict__ w2, float* __restrict__ biasT) {
    __shared__ float red[4][8];
    const int bid = blockIdx.x;
    const int tid = threadIdx.x;

    if (bid < 4096) {
        const int xcd = bid & 7;
        const int i = bid >> 3;
        const int rowblk = xcd * 128 + (i >> 2);
        const int c = i & 3;
        const int g = tid & 7;
        const int tseg = tid >> 3;
        const int tok0 = tseg * 4;
        const float* src = x + ((size_t)(rowblk >> 7) * 256 + c * 64 + g * 8) * 16384
                             + (rowblk & 127) * 128 + tok0;
        float4 v[8];
        #pragma unroll
        for (int j = 0; j < 8; ++j)
            v[j] = *(const float4*)(src + (size_t)j * 16384);
        u16x8 o0, o1, o2, o3;
        #pragma unroll
        for (int j = 0; j < 8; ++j) {
            o0[j] = f2b(v[j].x);
            o1[j] = f2b(v[j].y);
            o2[j] = f2b(v[j].z);
            o3[j] = f2b(v[j].w);
        }
        const int s0 = g ^ ((tseg ^ (tok0 + 0)) & 7);
        const int s1 = g ^ ((tseg ^ (tok0 + 1)) & 7);
        const int s2 = g ^ ((tseg ^ (tok0 + 2)) & 7);
        const int s3 = g ^ ((tseg ^ (tok0 + 3)) & 7);
        u16* dst = xt + ((size_t)rowblk * 4 + c) * 8192;
        *(u16x8*)&dst[(tok0 + 0) * 64 + (s0 << 3)] = o0;
        *(u16x8*)&dst[(tok0 + 1) * 64 + (s1 << 3)] = o1;
        *(u16x8*)&dst[(tok0 + 2) * 64 + (s2 << 3)] = o2;
        *(u16x8*)&dst[(tok0 + 3) * 64 + (s3 << 3)] = o3;
    } else if (bid < 4864) {
        const int id = (bid - 4096) * 256 + tid;
        if (id < 196608) qkvwb[id] = f2b(qkvw[id]);
        if (id < 65536)  pjwb[id]  = f2b(pjw[id]);
    } else {
        const int p = bid - 4864;
        const int d = tid;
        const int d0 = p / 15, d1 = p % 15;
        const float v0 = (float)(d0 - 7) * (8.0f / 7.0f);
        const float v1 = (float)(d1 - 7) * (8.0f / 7.0f);
        const float t0 = copysignf(log2f(fabsf(v0) + 1.0f) * (1.0f / 3.0f), v0);
        const float t1 = copysignf(log2f(fabsf(v1) + 1.0f) * (1.0f / 3.0f), v1);
        const float h = fmaxf(t0 * w1[2 * d] + t1 * w1[2 * d + 1] + b1[d], 0.0f);
        float s[8];
        #pragma unroll
        for (int hh = 0; hh < 8; ++hh) s[hh] = h * w2[hh * 256 + d];
        #pragma unroll
        for (int m = 1; m < 64; m <<= 1)
            #pragma unroll
            for (int hh = 0; hh < 8; ++hh) s[hh] += __shfl_xor(s[hh], m, 64);
        const int wave = d >> 6, l = d & 63;
        if (l == 0)
            #pragma unroll
            for (int hh = 0; hh < 8; ++hh) red[wave][hh] = s[hh];
        __syncthreads();
        const int a  = d0 - 7, bb = d1 - 7;
        const int na = 8 - (a  < 0 ? -a  : a);
        const int nb = 8 - (bb < 0 ? -bb : bb);
        if (tid < na * nb) {
            const int i2 = tid / nb, j2 = tid % nb;
            const int k_hi = (a  < 0 ? -a  : 0) + i2;
            const int q_hi = k_hi + a;
            const int k_lo = (bb < 0 ? -bb : 0) + j2;
            const int q_lo = k_lo + bb;
            const int kq = k_hi * 8 + k_lo, q = q_hi * 8 + q_lo;
            #pragma unroll
            for (int hh = 0; hh < 8; ++hh) {
                const float sum = red[0][hh] + red[1][hh] + red[2][hh] + red[3][hh];
                biasT[hh * 4096 + kq * 64 + q] = 16.0f / (1.0f + expf(-sum));
            }
        }
    }
}

// ---------------------------------------------------------------- qkv -----
// T4 counted-vmcnt pipeline (R19) + LDS-bounce coalesced epilogue: the old
// u16x4 stores hit 64 distinct lines per instruction (512B lane stride);
// bounce via per-wave 8KB LDS tile (Xs[1..2], free at epilogue) turns the
// writeout into 16B stores with 8 lanes covering one contiguous 128B run.
__global__ __launch_bounds__(256, 3) void k_qkv(
    const u16* __restrict__ xt, const u16* __restrict__ qkvw,
    const float* __restrict__ qkvb,
    u16* __restrict__ gq, u16* __restrict__ gk, u16* __restrict__ wv_g) {
    __shared__ __align__(16) u16 Xs[3][8192];  // 3 bufs x [128 tok][64 ch]

    const int bid = blockIdx.x;                 // 6144 = 8 xcd * 128 rowblk * 6 ny
    const int xcd = bid & 7;
    const int idx = bid >> 3;
    const int ny = idx % 6;
    const int rowblk = xcd * 128 + idx / 6;
    const int b = rowblk >> 7, row = rowblk & 127;
    const int which = ny >> 1, half = ny & 1;

    const int tid = threadIdx.x;
    const int wave = tid >> 6, l = tid & 63, col = l & 15, quad = l >> 4;
    const int th = wave >> 1;
    const int oq = wave & 1;
    const int obase = half * 128 + oq * 64;

    int orow[4];
    #pragma unroll
    for (int nt = 0; nt < 4; ++nt) {
        const int oo = obase + nt * 16 + col;
        orow[nt] = (oo >> 5) * 96 + which * 32 + (oo & 31);
    }

    f32x4 acc[4][4];                            // [nt(och)][mt(tok)]
    #pragma unroll
    for (int i = 0; i < 4; ++i)
        #pragma unroll
        for (int j = 0; j < 4; ++j) acc[i][j] = f32x4{0.f, 0.f, 0.f, 0.f};

    const u16* xtb = xt + (size_t)rowblk * 32768;

    auto stage = [&](int c, int buf) {
        const u16* src = xtb + c * 8192 + wave * 2048 + l * 8;
        u16* dst = &Xs[buf][wave * 2048];
        #pragma unroll
        for (int i = 0; i < 4; ++i)
            gload_lds16(src + i * 512, dst + i * 512);
    };
    auto loadW = [&](int c, bf16x8* bw) {
        #pragma unroll
        for (int kk = 0; kk < 2; ++kk)
            #pragma unroll
            for (int nt = 0; nt < 4; ++nt)
                bw[kk * 4 + nt] = *(const bf16x8*)&qkvw[(size_t)orow[nt] * 256 +
                                                        c * 64 + kk * 32 + quad * 8];
    };
    auto gemm = [&](int buf, const bf16x8* bw) {
        #pragma unroll
        for (int kk = 0; kk < 2; ++kk) {
            const int lchunk = kk * 4 + quad;
            bf16x8 af[4];
            #pragma unroll
            for (int mt = 0; mt < 4; ++mt) {
                const int tok = th * 64 + mt * 16 + col;
                const int slot = lchunk ^ (((tok >> 2) ^ tok) & 7);
                af[mt] = *(const bf16x8*)&Xs[buf][tok * 64 + (slot << 3)];
            }
            #pragma unroll
            for (int nt = 0; nt < 4; ++nt)
                #pragma unroll
                for (int mt = 0; mt < 4; ++mt)
                    acc[nt][mt] = __builtin_amdgcn_mfma_f32_16x16x32_bf16(
                        bw[kk * 4 + nt], af[mt], acc[nt][mt], 0, 0, 0);
        }
    };

    bf16x8 bwA[8], bwB[8];
    stage(0, 0);
    stage(1, 1);
    loadW(0, bwA);
    asm volatile("s_waitcnt vmcnt(12)" ::: "memory");
    __builtin_amdgcn_s_barrier();
    #pragma unroll
    for (int c = 0; c < 4; ++c) {
        if (c < 2) stage(c + 2, (c + 2) % 3);        // prefetch distance 2
        if (c < 3) loadW(c + 1, (c & 1) ? bwA : bwB);
        gemm(c % 3, (c & 1) ? bwB : bwA);
        if (c < 3) {
            if (c == 2) asm volatile("s_waitcnt vmcnt(8)" ::: "memory");
            else        asm volatile("s_waitcnt vmcnt(12)" ::: "memory");
            __builtin_amdgcn_s_barrier();
        }
    }

    // ---- epilogue: bias + norm into per-wave LDS tile (swizzled) ----
    // Wave region: Xs[1..2], 8KB each: [64 tok][64 och] u16. gemm(3) reads
    // only buf 0, so bufs 1-2 are free; same-wave LDS deps need no barrier.
    u16* const Ys = &Xs[0][0] + 8192 + wave * 4096;
    const int hA = obase >> 5;
    f32x4 bqv[4];
    #pragma unroll
    for (int nt = 0; nt < 4; ++nt) {
        const int oo = obase + nt * 16 + quad * 4;
        bqv[nt] = *(const f32x4*)&qkvb[(oo >> 5) * 96 + which * 32 + (oo & 31)];
    }
    #pragma unroll
    for (int mt = 0; mt < 4; ++mt) {
        const int tok_off = mt * 16 + col;          // 0..63 within wave
        float v[4][4];
        #pragma unroll
        for (int nt = 0; nt < 4; ++nt)
            #pragma unroll
            for (int r = 0; r < 4; ++r)
                v[nt][r] = acc[nt][mt][r] + bqv[nt][r];
        if (which < 2) {
            float sA = 0.f, sB = 0.f;
            #pragma unroll
            for (int r = 0; r < 4; ++r) {
                sA += v[0][r] * v[0][r] + v[1][r] * v[1][r];
                sB += v[2][r] * v[2][r] + v[3][r] * v[3][r];
            }
            sA += __shfl_xor(sA, 16, 64);
            sA += __shfl_xor(sA, 32, 64);
            sB += __shfl_xor(sB, 16, 64);
            sB += __shfl_xor(sB, 32, 64);
            const float iA = 1.0f / fmaxf(sqrtf(sA), 1e-12f);
            const float iB = 1.0f / fmaxf(sqrtf(sB), 1e-12f);
            #pragma unroll
            for (int r = 0; r < 4; ++r) {
                v[0][r] *= iA; v[1][r] *= iA;
                v[2][r] *= iB; v[3][r] *= iB;
            }
        }
        #pragma unroll
        for (int nt = 0; nt < 4; ++nt) {
            u16x4 ov;
            #pragma unroll
            for (int r = 0; r < 4; ++r) ov[r] = f2b(v[nt][r]);
            const int c8 = nt * 4 + quad;                       // 8B slot 0..15
            const int c8p = c8 ^ ((tok_off & 3) << 2);          // bank swizzle
            *(u16x4*)&Ys[tok_off * 64 + c8p * 4] = ov;
        }
    }

    // ---- coalesced writeout: 8 lanes cover one contiguous 128B och-run ----
    #pragma unroll
    for (int it = 0; it < 8; ++it) {
        const int tok_off = it * 8 + (l >> 3);      // 0..63
        const int c16 = l & 7;                      // 16B chunk (8 och)
        const int c16p = c16 ^ ((tok_off & 3) << 1);
        const u16x8 val = *(const u16x8*)&Ys[tok_off * 64 + c16p * 8];
        const int tok = th * 64 + tok_off;
        const int win = b * 256 + (row >> 3) * 16 + (tok >> 3);
        const int tk = (row & 7) * 8 + (tok & 7);
        if (which == 2) {
            *(u16x8*)&wv_g[((size_t)win * 64 + tk) * 256 + obase + c16 * 8] = val;
        } else {
            u16* G = (which == 0) ? gq : gk;
            const int h = hA + (c16 >> 2);
            const int d = (c16 & 3) * 8;
            *(u16x8*)&G[((size_t)(win * 8 + h) * 64 + tk) * 32 + d] = val;
        }
    }
}

// ---------------------------------------------------------------- attn ----
// R18 verbatim: S^T layout, in-register softmax, P^T from regs, XCD-aligned.
__global__ __launch_bounds__(256, 3) void k_attn3(
    const u16* __restrict__ gq, const u16* __restrict__ gk,
    const u16* __restrict__ wv_g,
    const float* __restrict__ lsc, const float* __restrict__ biasT,
    u16* __restrict__ wout_g) {
    __shared__ __align__(16) u16 scr[4][2048];  // per wave: v_t only

    const int tid = threadIdx.x;
    const int wave = tid >> 6, l = tid & 63, col = l & 15, quad = l >> 4;
    const int bid = blockIdx.x;                 // 4096 = 8 xcd * 512
    const int xcd = bid & 7;
    const int jl = (bid >> 3) * 4 + wave;       // 0..2047 per xcd
    const int h = jl >> 8;
    const int win = xcd * 256 + (jl & 255);
    u16* const v_t = scr[wave];  // [32 d][64 pi-slot] swz(d&7)

    u16x8 sv[4];
    #pragma unroll
    for (int it = 0; it < 4; ++it) {
        const int idx = it * 64 + l;
        const int tok = idx & 63, dblk = idx >> 6;
        sv[it] = *(const u16x8*)&wv_g[((size_t)win * 64 + tok) * 256 + h * 32 + dblk * 8];
    }
    const u16* const qbp = gq + (size_t)(win * 8 + h) * 2048;
    const u16* const kbp = gk + (size_t)(win * 8 + h) * 2048;
    bf16x8 ak[4], bq[4];
    #pragma unroll
    for (int mt = 0; mt < 4; ++mt)
        ak[mt] = *(const bf16x8*)&kbp[(mt * 16 + col) * 32 + quad * 8];
    #pragma unroll
    for (int nt = 0; nt < 4; ++nt)
        bq[nt] = *(const bf16x8*)&qbp[(nt * 16 + col) * 32 + quad * 8];

    #pragma unroll
    for (int it = 0; it < 4; ++it) {
        const int idx = it * 64 + l;
        const int tok = idx & 63, dblk = idx >> 6;
        const int g = (tok >> 5) * 4 + ((tok >> 2) & 3);
        const int jj = ((tok >> 4) & 1) * 4 + (tok & 3);
        #pragma unroll
        for (int j = 0; j < 8; ++j) {
            const int d = dblk * 8 + j;
            v_t[d * 64 + (((g ^ (d & 7)) << 3) | jj)] = sv[it][j];
        }
    }

    const f32x4 zero4 = {0.f, 0.f, 0.f, 0.f};
    f32x4 sacc[4][4];
    #pragma unroll
    for (int mt = 0; mt < 4; ++mt)
        #pragma unroll
        for (int nt = 0; nt < 4; ++nt)
            sacc[mt][nt] = __builtin_amdgcn_mfma_f32_16x16x32_bf16(ak[mt], bq[nt], zero4, 0, 0, 0);

    const float ls = expf(fminf(lsc[h], 4.6051701859880914f));
    const float* bT = biasT + h * 4096;
    #pragma unroll
    for (int nt = 0; nt < 4; ++nt) {
        const int q = nt * 16 + col;
        float v[4][4];
        float mx = -1e30f;
        #pragma unroll
        for (int mt = 0; mt < 4; ++mt)
            #pragma unroll
            for (int r = 0; r < 4; ++r) {
                v[mt][r] = sacc[mt][nt][r] * ls + bT[(mt * 16 + quad * 4 + r) * 64 + q];
                mx = fmaxf(mx, v[mt][r]);
            }
        mx = fmaxf(mx, __shfl_xor(mx, 16, 64));
        mx = fmaxf(mx, __shfl_xor(mx, 32, 64));
        float s = 0.f;
        #pragma unroll
        for (int mt = 0; mt < 4; ++mt)
            #pragma unroll
            for (int r = 0; r < 4; ++r) {
                v[mt][r] = expf(v[mt][r] - mx);
                s += v[mt][r];
            }
        s += __shfl_xor(s, 16, 64);
        s += __shfl_xor(s, 32, 64);
        const float inv = 1.0f / s;
        #pragma unroll
        for (int mt = 0; mt < 4; ++mt)
            #pragma unroll
            for (int r = 0; r < 4; ++r)
                sacc[mt][nt][r] = v[mt][r] * inv;
    }

    f32x4 oacc[2][4];
    #pragma unroll
    for (int i = 0; i < 2; ++i)
        #pragma unroll
        for (int j = 0; j < 4; ++j) oacc[i][j] = zero4;
    #pragma unroll
    for (int kk = 0; kk < 2; ++kk) {
        bf16x8 av[2];
        #pragma unroll
        for (int dt = 0; dt < 2; ++dt) {
            const int d = dt * 16 + col;
            av[dt] = *(const bf16x8*)&v_t[d * 64 + (((kk * 4 + quad) ^ (d & 7)) << 3)];
        }
        #pragma unroll
        for (int nt = 0; nt < 4; ++nt) {
            union { u16x8 u; bf16x8 b; } pk;
            #pragma unroll
            for (int j = 0; j < 4; ++j) {
                pk.u[j]     = f2b(sacc[kk * 2][nt][j]);
                pk.u[j + 4] = f2b(sacc[kk * 2 + 1][nt][j]);
            }
            #pragma unroll
            for (int dt = 0; dt < 2; ++dt)
                oacc[dt][nt] = __builtin_amdgcn_mfma_f32_16x16x32_bf16(
                    av[dt], pk.b, oacc[dt][nt], 0, 0, 0);
        }
    }
    #pragma unroll
    for (int dt = 0; dt < 2; ++dt)
        #pragma unroll
        for (int qt = 0; qt < 4; ++qt) {
            const int t = qt * 16 + col;
            u16x4 ov;
            #pragma unroll
            for (int r = 0; r < 4; ++r) ov[r] = f2b(oacc[dt][qt][r]);
            *(u16x4*)&wout_g[((size_t)win * 64 + t) * 256 + h * 32 + dt * 16 + quad * 4] = ov;
        }
}

// ---------------------------------------------------------------- proj ----
// R18 verbatim: operand-swapped GEMM, float4 stores, XCD-aligned win map.
__global__ __launch_bounds__(256, 4) void k_proj(
    const u16* __restrict__ wout_g, const u16* __restrict__ wv_g,
    const float* __restrict__ pe_w, const float* __restrict__ pe_b,
    const u16* __restrict__ pjw, const float* __restrict__ pjb,
    float* __restrict__ out) {
    __shared__ __align__(16) u16 y_s[64 * 256];
    const int bid0 = blockIdx.x;                // 2048 = 8 xcd * 256
    const int win = (bid0 & 7) * 256 + (bid0 >> 3);
    const int b = win >> 8;
    const int h0 = ((win >> 4) & 15) * 8;
    const int w0 = (win & 15) * 8;
    const int tid = threadIdx.x;
    const int cg = tid & 31, ch = cg * 8;
    const int psub = tid >> 5;

    float pw[9][8];
    #pragma unroll
    for (int j = 0; j < 8; ++j)
        #pragma unroll
        for (int k = 0; k < 9; ++k) pw[k][j] = pe_w[(ch + j) * 9 + k];
    float pb[8];
    #pragma unroll
    for (int j = 0; j < 8; ++j) pb[j] = pe_b[ch + j];

    for (int it = 0; it < 8; ++it) {
        const int p = it * 8 + psub;
        const int gh = h0 + (p >> 3), gw = w0 + (p & 7);
        float a[8];
        {
            const bf16x8 ov = *(const bf16x8*)&wout_g[((size_t)win * 64 + p) * 256 + ch];
            #pragma unroll
            for (int j = 0; j < 8; ++j) a[j] = b2f((u16)ov[j]) + pb[j];
        }
        #pragma unroll
        for (int dy = -1; dy <= 1; ++dy)
            #pragma unroll
            for (int dx = -1; dx <= 1; ++dx) {
                const int hh = gh + dy, ww2 = gw + dx;
                if (hh < 0 || hh >= 128 || ww2 < 0 || ww2 >= 128) continue;
                const int nwin = b * 256 + (hh >> 3) * 16 + (ww2 >> 3);
                const int ntk = (hh & 7) * 8 + (ww2 & 7);
                const bf16x8 vv = *(const bf16x8*)&wv_g[((size_t)nwin * 64 + ntk) * 256 + ch];
                const int k = (dy + 1) * 3 + (dx + 1);
                #pragma unroll
                for (int j = 0; j < 8; ++j) a[j] += b2f((u16)vv[j]) * pw[k][j];
            }
        u16x8 tmp;
        #pragma unroll
        for (int j = 0; j < 8; ++j) tmp[j] = f2b(a[j]);
        *(u16x8*)&y_s[p * 256 + (((ch >> 3) ^ (p & 7)) << 3)] = tmp;
    }
    __syncthreads();

    const int wave = tid >> 6, l = tid & 63;
    const int col = l & 15, quad = l >> 4;
    const f32x4 zero4 = {0.f, 0.f, 0.f, 0.f};
    f32x4 macc[4][4];                    // [pt(tok)][ot(och)]
    #pragma unroll
    for (int pt = 0; pt < 4; ++pt)
        #pragma unroll
        for (int ot = 0; ot < 4; ++ot) macc[pt][ot] = zero4;
    const int ob = wave * 64;
    for (int kk = 0; kk < 8; ++kk) {
        const int cb = kk * 32 + quad * 8;
        bf16x8 aw[4], by[4];
        #pragma unroll
        for (int ot = 0; ot < 4; ++ot)
            aw[ot] = *(const bf16x8*)&pjw[(size_t)(ob + ot * 16 + col) * 256 + cb];
        #pragma unroll
        for (int pt = 0; pt < 4; ++pt) {
            const int p = pt * 16 + col;
            by[pt] = *(const bf16x8*)&y_s[p * 256 + (((cb >> 3) ^ (p & 7)) << 3)];
        }
        #pragma unroll
        for (int pt = 0; pt < 4; ++pt)
            #pragma unroll
            for (int ot = 0; ot < 4; ++ot)
                macc[pt][ot] = __builtin_amdgcn_mfma_f32_16x16x32_bf16(
                    by[pt], aw[ot], macc[pt][ot], 0, 0, 0);
    }
    #pragma unroll
    for (int ot = 0; ot < 4; ++ot) {
        const int o = ob + ot * 16 + col;
        const float pbv = pjb[o];
        #pragma unroll
        for (int pt = 0; pt < 4; ++pt) {
            const int p0 = pt * 16 + quad * 4;
            float4 ov;
            ov.x = macc[pt][ot][0] + pbv;
            ov.y = macc[pt][ot][1] + pbv;
            ov.z = macc[pt][ot][2] + pbv;
            ov.w = macc[pt][ot][3] + pbv;
            *(float4*)&out[((size_t)(b * 256 + o)) * 16384 +
                           (h0 + (p0 >> 3)) * 128 + w0 + (p0 & 7)] = ov;
        }
    }
}

// -------------------------------------------------------------- launch ----
extern "C" void kernel_launch(void* const* d_in, const int* in_sizes, int n_in,
                              void* d_out, int out_size, void* d_ws, size_t ws_size,
                              hipStream_t stream) {
    const float* x    = (const float*)d_in[0];
    const float* qkvw = (const float*)d_in[1];
    const float* qkvb = (const float*)d_in[2];
    const float* pjw  = (const float*)d_in[3];
    const float* pjb  = (const float*)d_in[4];
    const float* pew  = (const float*)d_in[5];
    const float* peb  = (const float*)d_in[6];
    const float* lsc  = (const float*)d_in[7];
    const float* w1   = (const float*)d_in[8];
    const float* b1   = (const float*)d_in[9];
    const float* w2   = (const float*)d_in[10];

    char* ws = (char*)d_ws;
    u16* wv_b    = (u16*)(ws);                                    // 64 MiB
    u16* wout_b  = (u16*)(ws + (64ull << 20));                    // 64 MiB
    u16* qkvwb   = (u16*)(ws + (128ull << 20));                   // 384 KiB
    u16* pjwb    = (u16*)(ws + (128ull << 20) + 393216);          // 128 KiB
    float* biasT = (float*)(ws + (128ull << 20) + 393216 + 131072); // 128 KiB

    u16* xt = wout_b;
    u16* gq = (u16*)d_out;
    u16* gk = gq + 33554432u;

    hipLaunchKernelGGL(k_pre, dim3(5089), dim3(256), 0, stream,
                       x, xt, qkvw, pjw, qkvwb, pjwb, w1, b1, w2, biasT);
    hipLaunchKernelGGL(k_qkv, dim3(6144), dim3(256), 0, stream,
                       xt, qkvwb, qkvb, gq, gk, wv_b);
    hipLaunchKernelGGL(k_attn3, dim3(4096), dim3(256), 0, stream,
                       gq, gk, wv_b, lsc, biasT, wout_b);
    hipLaunchKernelGGL(k_proj, dim3(2048), dim3(256), 0, stream,
                       wout_b, wv_b, pew, peb, pjwb, pjb, (float*)d_out);
}

// Round 21
// 329.938 us; speedup vs baseline: 2.0725x; 1.0180x over previous
//
#include <hip/hip_runtime.h>

typedef unsigned short u16;
typedef unsigned int u32;
typedef short bf16x8 __attribute__((ext_vector_type(8)));
typedef float f32x4 __attribute__((ext_vector_type(4)));
typedef unsigned short u16x8 __attribute__((ext_vector_type(8)));
typedef unsigned short u16x4 __attribute__((ext_vector_type(4)));

#define DEVFN static __device__ __forceinline__

DEVFN u16 f2b(float f) {
    u32 u = __builtin_bit_cast(u32, f);
    u += 0x7FFFu + ((u >> 16) & 1u);
    return (u16)(u >> 16);
}
DEVFN float b2f(u16 h) {
    u32 u = ((u32)h) << 16;
    return __builtin_bit_cast(float, u);
}

typedef const __attribute__((address_space(1))) unsigned int glb_u32;
typedef __attribute__((address_space(3))) unsigned int lds_u32;
DEVFN void gload_lds16(const u16* g, u16* l) {
    __builtin_amdgcn_global_load_lds((glb_u32*)g, (lds_u32*)l, 16, 0, 0);
}

// ----------------------------------------------------------------- pre ----
// Fused pre-pass (R18 verbatim): xcvt | weight convert | CPB->biasT scatter.
__global__ __launch_bounds__(256) void k_pre(
    const float* __restrict__ x, u16* __restrict__ xt,
    const float* __restrict__ qkvw, const float* __restrict__ pjw,
    u16* __restrict__ qkvwb, u16* __restrict__ pjwb,
    const float* __restrict__ w1, const float* __restrict__ b1,
    const float* __restrict__ w2, float* __restrict__ biasT) {
    __shared__ float red[4][8];
    const int bid = blockIdx.x;
    const int tid = threadIdx.x;

    if (bid < 4096) {
        const int xcd = bid & 7;
        const int i = bid >> 3;
        const int rowblk = xcd * 128 + (i >> 2);
        const int c = i & 3;
        const int g = tid & 7;
        const int tseg = tid >> 3;
        const int tok0 = tseg * 4;
        const float* src = x + ((size_t)(rowblk >> 7) * 256 + c * 64 + g * 8) * 16384
                             + (rowblk & 127) * 128 + tok0;
        float4 v[8];
        #pragma unroll
        for (int j = 0; j < 8; ++j)
            v[j] = *(const float4*)(src + (size_t)j * 16384);
        u16x8 o0, o1, o2, o3;
        #pragma unroll
        for (int j = 0; j < 8; ++j) {
            o0[j] = f2b(v[j].x);
            o1[j] = f2b(v[j].y);
            o2[j] = f2b(v[j].z);
            o3[j] = f2b(v[j].w);
        }
        const int s0 = g ^ ((tseg ^ (tok0 + 0)) & 7);
        const int s1 = g ^ ((tseg ^ (tok0 + 1)) & 7);
        const int s2 = g ^ ((tseg ^ (tok0 + 2)) & 7);
        const int s3 = g ^ ((tseg ^ (tok0 + 3)) & 7);
        u16* dst = xt + ((size_t)rowblk * 4 + c) * 8192;
        *(u16x8*)&dst[(tok0 + 0) * 64 + (s0 << 3)] = o0;
        *(u16x8*)&dst[(tok0 + 1) * 64 + (s1 << 3)] = o1;
        *(u16x8*)&dst[(tok0 + 2) * 64 + (s2 << 3)] = o2;
        *(u16x8*)&dst[(tok0 + 3) * 64 + (s3 << 3)] = o3;
    } else if (bid < 4864) {
        const int id = (bid - 4096) * 256 + tid;
        if (id < 196608) qkvwb[id] = f2b(qkvw[id]);
        if (id < 65536)  pjwb[id]  = f2b(pjw[id]);
    } else {
        const int p = bid - 4864;
        const int d = tid;
        const int d0 = p / 15, d1 = p % 15;
        const float v0 = (float)(d0 - 7) * (8.0f / 7.0f);
        const float v1 = (float)(d1 - 7) * (8.0f / 7.0f);
        const float t0 = copysignf(log2f(fabsf(v0) + 1.0f) * (1.0f / 3.0f), v0);
        const float t1 = copysignf(log2f(fabsf(v1) + 1.0f) * (1.0f / 3.0f), v1);
        const float h = fmaxf(t0 * w1[2 * d] + t1 * w1[2 * d + 1] + b1[d], 0.0f);
        float s[8];
        #pragma unroll
        for (int hh = 0; hh < 8; ++hh) s[hh] = h * w2[hh * 256 + d];
        #pragma unroll
        for (int m = 1; m < 64; m <<= 1)
            #pragma unroll
            for (int hh = 0; hh < 8; ++hh) s[hh] += __shfl_xor(s[hh], m, 64);
        const int wave = d >> 6, l = d & 63;
        if (l == 0)
            #pragma unroll
            for (int hh = 0; hh < 8; ++hh) red[wave][hh] = s[hh];
        __syncthreads();
        const int a  = d0 - 7, bb = d1 - 7;
        const int na = 8 - (a  < 0 ? -a  : a);
        const int nb = 8 - (bb < 0 ? -bb : bb);
        if (tid < na * nb) {
            const int i2 = tid / nb, j2 = tid % nb;
            const int k_hi = (a  < 0 ? -a  : 0) + i2;
            const int q_hi = k_hi + a;
            const int k_lo = (bb < 0 ? -bb : 0) + j2;
            const int q_lo = k_lo + bb;
            const int kq = k_hi * 8 + k_lo, q = q_hi * 8 + q_lo;
            #pragma unroll
            for (int hh = 0; hh < 8; ++hh) {
                const float sum = red[0][hh] + red[1][hh] + red[2][hh] + red[3][hh];
                biasT[hh * 4096 + kq * 64 + q] = 16.0f / (1.0f + expf(-sum));
            }
        }
    }
}

// ---------------------------------------------------------------- qkv -----
// R20 verbatim: T4 counted-vmcnt pipeline + LDS-bounce coalesced epilogue.
__global__ __launch_bounds__(256, 3) void k_qkv(
    const u16* __restrict__ xt, const u16* __restrict__ qkvw,
    const float* __restrict__ qkvb,
    u16* __restrict__ gq, u16* __restrict__ gk, u16* __restrict__ wv_g) {
    __shared__ __align__(16) u16 Xs[3][8192];  // 3 bufs x [128 tok][64 ch]

    const int bid = blockIdx.x;                 // 6144 = 8 xcd * 128 rowblk * 6 ny
    const int xcd = bid & 7;
    const int idx = bid >> 3;
    const int ny = idx % 6;
    const int rowblk = xcd * 128 + idx / 6;
    const int b = rowblk >> 7, row = rowblk & 127;
    const int which = ny >> 1, half = ny & 1;

    const int tid = threadIdx.x;
    const int wave = tid >> 6, l = tid & 63, col = l & 15, quad = l >> 4;
    const int th = wave >> 1;
    const int oq = wave & 1;
    const int obase = half * 128 + oq * 64;

    int orow[4];
    #pragma unroll
    for (int nt = 0; nt < 4; ++nt) {
        const int oo = obase + nt * 16 + col;
        orow[nt] = (oo >> 5) * 96 + which * 32 + (oo & 31);
    }

    f32x4 acc[4][4];                            // [nt(och)][mt(tok)]
    #pragma unroll
    for (int i = 0; i < 4; ++i)
        #pragma unroll
        for (int j = 0; j < 4; ++j) acc[i][j] = f32x4{0.f, 0.f, 0.f, 0.f};

    const u16* xtb = xt + (size_t)rowblk * 32768;

    auto stage = [&](int c, int buf) {
        const u16* src = xtb + c * 8192 + wave * 2048 + l * 8;
        u16* dst = &Xs[buf][wave * 2048];
        #pragma unroll
        for (int i = 0; i < 4; ++i)
            gload_lds16(src + i * 512, dst + i * 512);
    };
    auto loadW = [&](int c, bf16x8* bw) {
        #pragma unroll
        for (int kk = 0; kk < 2; ++kk)
            #pragma unroll
            for (int nt = 0; nt < 4; ++nt)
                bw[kk * 4 + nt] = *(const bf16x8*)&qkvw[(size_t)orow[nt] * 256 +
                                                        c * 64 + kk * 32 + quad * 8];
    };
    auto gemm = [&](int buf, const bf16x8* bw) {
        #pragma unroll
        for (int kk = 0; kk < 2; ++kk) {
            const int lchunk = kk * 4 + quad;
            bf16x8 af[4];
            #pragma unroll
            for (int mt = 0; mt < 4; ++mt) {
                const int tok = th * 64 + mt * 16 + col;
                const int slot = lchunk ^ (((tok >> 2) ^ tok) & 7);
                af[mt] = *(const bf16x8*)&Xs[buf][tok * 64 + (slot << 3)];
            }
            #pragma unroll
            for (int nt = 0; nt < 4; ++nt)
                #pragma unroll
                for (int mt = 0; mt < 4; ++mt)
                    acc[nt][mt] = __builtin_amdgcn_mfma_f32_16x16x32_bf16(
                        bw[kk * 4 + nt], af[mt], acc[nt][mt], 0, 0, 0);
        }
    };

    bf16x8 bwA[8], bwB[8];
    stage(0, 0);
    stage(1, 1);
    loadW(0, bwA);
    asm volatile("s_waitcnt vmcnt(12)" ::: "memory");
    __builtin_amdgcn_s_barrier();
    #pragma unroll
    for (int c = 0; c < 4; ++c) {
        if (c < 2) stage(c + 2, (c + 2) % 3);        // prefetch distance 2
        if (c < 3) loadW(c + 1, (c & 1) ? bwA : bwB);
        gemm(c % 3, (c & 1) ? bwB : bwA);
        if (c < 3) {
            if (c == 2) asm volatile("s_waitcnt vmcnt(8)" ::: "memory");
            else        asm volatile("s_waitcnt vmcnt(12)" ::: "memory");
            __builtin_amdgcn_s_barrier();
        }
    }

    // ---- epilogue: bias + norm into per-wave LDS tile (swizzled) ----
    u16* const Ys = &Xs[0][0] + 8192 + wave * 4096;
    const int hA = obase >> 5;
    f32x4 bqv[4];
    #pragma unroll
    for (int nt = 0; nt < 4; ++nt) {
        const int oo = obase + nt * 16 + quad * 4;
        bqv[nt] = *(const f32x4*)&qkvb[(oo >> 5) * 96 + which * 32 + (oo & 31)];
    }
    #pragma unroll
    for (int mt = 0; mt < 4; ++mt) {
        const int tok_off = mt * 16 + col;          // 0..63 within wave
        float v[4][4];
        #pragma unroll
        for (int nt = 0; nt < 4; ++nt)
            #pragma unroll
            for (int r = 0; r < 4; ++r)
                v[nt][r] = acc[nt][mt][r] + bqv[nt][r];
        if (which < 2) {
            float sA = 0.f, sB = 0.f;
            #pragma unroll
            for (int r = 0; r < 4; ++r) {
                sA += v[0][r] * v[0][r] + v[1][r] * v[1][r];
                sB += v[2][r] * v[2][r] + v[3][r] * v[3][r];
            }
            sA += __shfl_xor(sA, 16, 64);
            sA += __shfl_xor(sA, 32, 64);
            sB += __shfl_xor(sB, 16, 64);
            sB += __shfl_xor(sB, 32, 64);
            const float iA = 1.0f / fmaxf(sqrtf(sA), 1e-12f);
            const float iB = 1.0f / fmaxf(sqrtf(sB), 1e-12f);
            #pragma unroll
            for (int r = 0; r < 4; ++r) {
                v[0][r] *= iA; v[1][r] *= iA;
                v[2][r] *= iB; v[3][r] *= iB;
            }
        }
        #pragma unroll
        for (int nt = 0; nt < 4; ++nt) {
            u16x4 ov;
            #pragma unroll
            for (int r = 0; r < 4; ++r) ov[r] = f2b(v[nt][r]);
            const int c8 = nt * 4 + quad;                       // 8B slot 0..15
            const int c8p = c8 ^ ((tok_off & 3) << 2);          // bank swizzle
            *(u16x4*)&Ys[tok_off * 64 + c8p * 4] = ov;
        }
    }

    // ---- coalesced writeout: 8 lanes cover one contiguous 128B och-run ----
    #pragma unroll
    for (int it = 0; it < 8; ++it) {
        const int tok_off = it * 8 + (l >> 3);      // 0..63
        const int c16 = l & 7;                      // 16B chunk (8 och)
        const int c16p = c16 ^ ((tok_off & 3) << 1);
        const u16x8 val = *(const u16x8*)&Ys[tok_off * 64 + c16p * 8];
        const int tok = th * 64 + tok_off;
        const int win = b * 256 + (row >> 3) * 16 + (tok >> 3);
        const int tk = (row & 7) * 8 + (tok & 7);
        if (which == 2) {
            *(u16x8*)&wv_g[((size_t)win * 64 + tk) * 256 + obase + c16 * 8] = val;
        } else {
            u16* G = (which == 0) ? gq : gk;
            const int h = hA + (c16 >> 2);
            const int d = (c16 & 3) * 8;
            *(u16x8*)&G[((size_t)(win * 8 + h) * 64 + tk) * 32 + d] = val;
        }
    }
}

// ---------------------------------------------------------------- attn ----
// R20 + wout LDS-bounce: oacc -> v_t (dead after PV, wave-private) ->
// coalesced u16x8 writeout (4 lanes cover one token's contiguous 64B run;
// 4 instructions instead of 8 x 16-line scattered stores).
__global__ __launch_bounds__(256, 3) void k_attn3(
    const u16* __restrict__ gq, const u16* __restrict__ gk,
    const u16* __restrict__ wv_g,
    const float* __restrict__ lsc, const float* __restrict__ biasT,
    u16* __restrict__ wout_g) {
    __shared__ __align__(16) u16 scr[4][2048];  // per wave: v_t / out-bounce

    const int tid = threadIdx.x;
    const int wave = tid >> 6, l = tid & 63, col = l & 15, quad = l >> 4;
    const int bid = blockIdx.x;                 // 4096 = 8 xcd * 512
    const int xcd = bid & 7;
    const int jl = (bid >> 3) * 4 + wave;       // 0..2047 per xcd
    const int h = jl >> 8;
    const int win = xcd * 256 + (jl & 255);
    u16* const v_t = scr[wave];  // [32 d][64 pi-slot] swz(d&7)

    u16x8 sv[4];
    #pragma unroll
    for (int it = 0; it < 4; ++it) {
        const int idx = it * 64 + l;
        const int tok = idx & 63, dblk = idx >> 6;
        sv[it] = *(const u16x8*)&wv_g[((size_t)win * 64 + tok) * 256 + h * 32 + dblk * 8];
    }
    const u16* const qbp = gq + (size_t)(win * 8 + h) * 2048;
    const u16* const kbp = gk + (size_t)(win * 8 + h) * 2048;
    bf16x8 ak[4], bq[4];
    #pragma unroll
    for (int mt = 0; mt < 4; ++mt)
        ak[mt] = *(const bf16x8*)&kbp[(mt * 16 + col) * 32 + quad * 8];
    #pragma unroll
    for (int nt = 0; nt < 4; ++nt)
        bq[nt] = *(const bf16x8*)&qbp[(nt * 16 + col) * 32 + quad * 8];

    #pragma unroll
    for (int it = 0; it < 4; ++it) {
        const int idx = it * 64 + l;
        const int tok = idx & 63, dblk = idx >> 6;
        const int g = (tok >> 5) * 4 + ((tok >> 2) & 3);
        const int jj = ((tok >> 4) & 1) * 4 + (tok & 3);
        #pragma unroll
        for (int j = 0; j < 8; ++j) {
            const int d = dblk * 8 + j;
            v_t[d * 64 + (((g ^ (d & 7)) << 3) | jj)] = sv[it][j];
        }
    }

    const f32x4 zero4 = {0.f, 0.f, 0.f, 0.f};
    f32x4 sacc[4][4];
    #pragma unroll
    for (int mt = 0; mt < 4; ++mt)
        #pragma unroll
        for (int nt = 0; nt < 4; ++nt)
            sacc[mt][nt] = __builtin_amdgcn_mfma_f32_16x16x32_bf16(ak[mt], bq[nt], zero4, 0, 0, 0);

    const float ls = expf(fminf(lsc[h], 4.6051701859880914f));
    const float* bT = biasT + h * 4096;
    #pragma unroll
    for (int nt = 0; nt < 4; ++nt) {
        const int q = nt * 16 + col;
        float v[4][4];
        float mx = -1e30f;
        #pragma unroll
        for (int mt = 0; mt < 4; ++mt)
            #pragma unroll
            for (int r = 0; r < 4; ++r) {
                v[mt][r] = sacc[mt][nt][r] * ls + bT[(mt * 16 + quad * 4 + r) * 64 + q];
                mx = fmaxf(mx, v[mt][r]);
            }
        mx = fmaxf(mx, __shfl_xor(mx, 16, 64));
        mx = fmaxf(mx, __shfl_xor(mx, 32, 64));
        float s = 0.f;
        #pragma unroll
        for (int mt = 0; mt < 4; ++mt)
            #pragma unroll
            for (int r = 0; r < 4; ++r) {
                v[mt][r] = expf(v[mt][r] - mx);
                s += v[mt][r];
            }
        s += __shfl_xor(s, 16, 64);
        s += __shfl_xor(s, 32, 64);
        const float inv = 1.0f / s;
        #pragma unroll
        for (int mt = 0; mt < 4; ++mt)
            #pragma unroll
            for (int r = 0; r < 4; ++r)
                sacc[mt][nt][r] = v[mt][r] * inv;
    }

    f32x4 oacc[2][4];
    #pragma unroll
    for (int i = 0; i < 2; ++i)
        #pragma unroll
        for (int j = 0; j < 4; ++j) oacc[i][j] = zero4;
    #pragma unroll
    for (int kk = 0; kk < 2; ++kk) {
        bf16x8 av[2];
        #pragma unroll
        for (int dt = 0; dt < 2; ++dt) {
            const int d = dt * 16 + col;
            av[dt] = *(const bf16x8*)&v_t[d * 64 + (((kk * 4 + quad) ^ (d & 7)) << 3)];
        }
        #pragma unroll
        for (int nt = 0; nt < 4; ++nt) {
            union { u16x8 u; bf16x8 b; } pk;
            #pragma unroll
            for (int j = 0; j < 4; ++j) {
                pk.u[j]     = f2b(sacc[kk * 2][nt][j]);
                pk.u[j + 4] = f2b(sacc[kk * 2 + 1][nt][j]);
            }
            #pragma unroll
            for (int dt = 0; dt < 2; ++dt)
                oacc[dt][nt] = __builtin_amdgcn_mfma_f32_16x16x32_bf16(
                    av[dt], pk.b, oacc[dt][nt], 0, 0, 0);
        }
    }

    // ---- bounce out^T through v_t (dead after PV): tile [64 tok][32 d] ----
    u16* const Ys = v_t;
    #pragma unroll
    for (int dt = 0; dt < 2; ++dt)
        #pragma unroll
        for (int qt = 0; qt < 4; ++qt) {
            const int t = qt * 16 + col;
            u16x4 ov;
            #pragma unroll
            for (int r = 0; r < 4; ++r) ov[r] = f2b(oacc[dt][qt][r]);
            const int s = dt * 4 + quad;            // 8B slot 0..7
            const int sp = s ^ ((t & 2) << 1);      // bank swizzle (even XOR)
            *(u16x4*)&Ys[t * 32 + sp * 4] = ov;
        }
    // ---- coalesced writeout: 4 lanes cover one token's 64B run ----
    #pragma unroll
    for (int it = 0; it < 4; ++it) {
        const int tt = it * 16 + (l >> 2);          // 0..63
        const int c16 = l & 3;                      // 16B chunk (8 d)
        const int c16p = c16 ^ (tt & 2);
        const u16x8 val = *(const u16x8*)&Ys[tt * 32 + c16p * 8];
        *(u16x8*)&wout_g[((size_t)win * 64 + tt) * 256 + h * 32 + c16 * 8] = val;
    }
}

// ---------------------------------------------------------------- proj ----
// R20 verbatim: operand-swapped GEMM, float4 stores, XCD-aligned win map.
__global__ __launch_bounds__(256, 4) void k_proj(
    const u16* __restrict__ wout_g, const u16* __restrict__ wv_g,
    const float* __restrict__ pe_w, const float* __restrict__ pe_b,
    const u16* __restrict__ pjw, const float* __restrict__ pjb,
    float* __restrict__ out) {
    __shared__ __align__(16) u16 y_s[64 * 256];
    const int bid0 = blockIdx.x;                // 2048 = 8 xcd * 256
    const int win = (bid0 & 7) * 256 + (bid0 >> 3);
    const int b = win >> 8;
    const int h0 = ((win >> 4) & 15) * 8;
    const int w0 = (win & 15) * 8;
    const int tid = threadIdx.x;
    const int cg = tid & 31, ch = cg * 8;
    const int psub = tid >> 5;

    float pw[9][8];
    #pragma unroll
    for (int j = 0; j < 8; ++j)
        #pragma unroll
        for (int k = 0; k < 9; ++k) pw[k][j] = pe_w[(ch + j) * 9 + k];
    float pb[8];
    #pragma unroll
    for (int j = 0; j < 8; ++j) pb[j] = pe_b[ch + j];

    for (int it = 0; it < 8; ++it) {
        const int p = it * 8 + psub;
        const int gh = h0 + (p >> 3), gw = w0 + (p & 7);
        float a[8];
        {
            const bf16x8 ov = *(const bf16x8*)&wout_g[((size_t)win * 64 + p) * 256 + ch];
            #pragma unroll
            for (int j = 0; j < 8; ++j) a[j] = b2f((u16)ov[j]) + pb[j];
        }
        #pragma unroll
        for (int dy = -1; dy <= 1; ++dy)
            #pragma unroll
            for (int dx = -1; dx <= 1; ++dx) {
                const int hh = gh + dy, ww2 = gw + dx;
                if (hh < 0 || hh >= 128 || ww2 < 0 || ww2 >= 128) continue;
                const int nwin = b * 256 + (hh >> 3) * 16 + (ww2 >> 3);
                const int ntk = (hh & 7) * 8 + (ww2 & 7);
                const bf16x8 vv = *(const bf16x8*)&wv_g[((size_t)nwin * 64 + ntk) * 256 + ch];
                const int k = (dy + 1) * 3 + (dx + 1);
                #pragma unroll
                for (int j = 0; j < 8; ++j) a[j] += b2f((u16)vv[j]) * pw[k][j];
            }
        u16x8 tmp;
        #pragma unroll
        for (int j = 0; j < 8; ++j) tmp[j] = f2b(a[j]);
        *(u16x8*)&y_s[p * 256 + (((ch >> 3) ^ (p & 7)) << 3)] = tmp;
    }
    __syncthreads();

    const int wave = tid >> 6, l = tid & 63;
    const int col = l & 15, quad = l >> 4;
    const f32x4 zero4 = {0.f, 0.f, 0.f, 0.f};
    f32x4 macc[4][4];                    // [pt(tok)][ot(och)]
    #pragma unroll
    for (int pt = 0; pt < 4; ++pt)
        #pragma unroll
        for (int ot = 0; ot < 4; ++ot) macc[pt][ot] = zero4;
    const int ob = wave * 64;
    for (int kk = 0; kk < 8; ++kk) {
        const int cb = kk * 32 + quad * 8;
        bf16x8 aw[4], by[4];
        #pragma unroll
        for (int ot = 0; ot < 4; ++ot)
            aw[ot] = *(const bf16x8*)&pjw[(size_t)(ob + ot * 16 + col) * 256 + cb];
        #pragma unroll
        for (int pt = 0; pt < 4; ++pt) {
            const int p = pt * 16 + col;
            by[pt] = *(const bf16x8*)&y_s[p * 256 + (((cb >> 3) ^ (p & 7)) << 3)];
        }
        #pragma unroll
        for (int pt = 0; pt < 4; ++pt)
            #pragma unroll
            for (int ot = 0; ot < 4; ++ot)
                macc[pt][ot] = __builtin_amdgcn_mfma_f32_16x16x32_bf16(
                    by[pt], aw[ot], macc[pt][ot], 0, 0, 0);
    }
    #pragma unroll
    for (int ot = 0; ot < 4; ++ot) {
        const int o = ob + ot * 16 + col;
        const float pbv = pjb[o];
        #pragma unroll
        for (int pt = 0; pt < 4; ++pt) {
            const int p0 = pt * 16 + quad * 4;
            float4 ov;
            ov.x = macc[pt][ot][0] + pbv;
            ov.y = macc[pt][ot][1] + pbv;
            ov.z = macc[pt][ot][2] + pbv;
            ov.w = macc[pt][ot][3] + pbv;
            *(float4*)&out[((size_t)(b * 256 + o)) * 16384 +
                           (h0 + (p0 >> 3)) * 128 + w0 + (p0 & 7)] = ov;
        }
    }
}

// -------------------------------------------------------------- launch ----
extern "C" void kernel_launch(void* const* d_in, const int* in_sizes, int n_in,
                              void* d_out, int out_size, void* d_ws, size_t ws_size,
                              hipStream_t stream) {
    const float* x    = (const float*)d_in[0];
    const float* qkvw = (const float*)d_in[1];
    const float* qkvb = (const float*)d_in[2];
    const float* pjw  = (const float*)d_in[3];
    const float* pjb  = (const float*)d_in[4];
    const float* pew  = (const float*)d_in[5];
    const float* peb  = (const float*)d_in[6];
    const float* lsc  = (const float*)d_in[7];
    const float* w1   = (const float*)d_in[8];
    const float* b1   = (const float*)d_in[9];
    const float* w2   = (const float*)d_in[10];

    char* ws = (char*)d_ws;
    u16* wv_b    = (u16*)(ws);                                    // 64 MiB
    u16* wout_b  = (u16*)(ws + (64ull << 20));                    // 64 MiB
    u16* qkvwb   = (u16*)(ws + (128ull << 20));                   // 384 KiB
    u16* pjwb    = (u16*)(ws + (128ull << 20) + 393216);          // 128 KiB
    float* biasT = (float*)(ws + (128ull << 20) + 393216 + 131072); // 128 KiB

    u16* xt = wout_b;
    u16* gq = (u16*)d_out;
    u16* gk = gq + 33554432u;

    hipLaunchKernelGGL(k_pre, dim3(5089), dim3(256), 0, stream,
                       x, xt, qkvw, pjw, qkvwb, pjwb, w1, b1, w2, biasT);
    hipLaunchKernelGGL(k_qkv, dim3(6144), dim3(256), 0, stream,
                       xt, qkvwb, qkvb, gq, gk, wv_b);
    hipLaunchKernelGGL(k_attn3, dim3(4096), dim3(256), 0, stream,
                       gq, gk, wv_b, lsc, biasT, wout_b);
    hipLaunchKernelGGL(k_proj, dim3(2048), dim3(256), 0, stream,
                       wout_b, wv_b, pew, peb, pjwb, pjb, (float*)d_out);
}